// Round 1
// baseline (1232.777 us; speedup 1.0000x reference)
//
#include <hip/hip_runtime.h>

// Problem constants
#define D_  128
#define T_  128
#define N_  32
#define H_  256
#define HK_ 64
#define P_  255           // 2T-1 evaluation points (t grid + midpoints)
#define SROW 8320         // 65*128: S row stride (64 hden rows + 1 fybar row)
#define NCH  33           // c-chunks of 2 over 65 rows
#define GSZ  32640        // 255*128

// workspace offsets (in floats)
#define OFF_YG   0                 // yg: T*D
#define OFF_M    16384             // spline M: T*D
#define OFF_WT   32768             // WT[c][j][i], c in 0..64 (row 64 = bk2): 65*16384
#define OFF_S    1097728           // S[p][c][j]: 255*8320
#define OFF_PART 3219328           // partial[cc][p][i]: 33*32640
#define OFF_G    4296448           // g[p][i]: 32640
// total = 4329088 floats = ~16.6 MiB of d_ws required

__global__ __launch_bounds__(256) void k_init(const float* __restrict__ z0,
                                              float* __restrict__ yg) {
  int idx = blockIdx.x * 256 + threadIdx.x;
  if (idx < T_ * D_) yg[idx] = z0[idx & (D_ - 1)];
}

// WT[c][j][i] = Wrow_c[i*128 + j], Wrow_c = Wk2 + c*16384 (c<64) or bk2 (c==64)
__global__ __launch_bounds__(256) void k_transpose(const float* __restrict__ Wk2,
                                                   const float* __restrict__ bk2,
                                                   float* __restrict__ WT) {
  int c = blockIdx.x;
  const float* src = (c < 64) ? (Wk2 + c * 16384) : bk2;
  __shared__ float tile[16384];   // XOR-swizzled to stay <=64KB, conflict-free
  #pragma unroll 8
  for (int k = 0; k < 64; ++k) {
    int idx = k * 256 + threadIdx.x;
    int i = idx >> 7, j = idx & 127;
    tile[j * 128 + (i ^ (j & 31))] = src[idx];
  }
  __syncthreads();
  float* dst = WT + c * 16384;
  #pragma unroll 8
  for (int k = 0; k < 64; ++k) {
    int idx = k * 256 + threadIdx.x;
    int jj = idx >> 7, ii = idx & 127;
    dst[idx] = tile[jj * 128 + (ii ^ (jj & 31))];
  }
}

// Natural cubic spline second-derivatives M (T,D) via Thomas algorithm.
// dp is staged through the M buffer itself (each thread owns one column).
__global__ __launch_bounds__(128) void k_spline(const float* __restrict__ t,
                                                const float* __restrict__ yg,
                                                float* __restrict__ M) {
  int d = threadIdx.x;  // 0..127, one column each
  __shared__ float tl[128];
  __shared__ float invh[128];
  __shared__ float cp[128];
  __shared__ float invm[128];
  tl[d] = t[d];
  __syncthreads();
  if (d < 127) invh[d] = 1.0f / (tl[d + 1] - tl[d]);
  if (d == 0) {
    float cprev = 0.0f;
    for (int i = 1; i <= 126; ++i) {
      float hm = tl[i] - tl[i - 1], hi = tl[i + 1] - tl[i];
      float m = 2.0f * (hm + hi) - hm * cprev;
      float im = 1.0f / m;
      invm[i] = im;
      cprev = hi * im;
      cp[i] = cprev;
    }
  }
  __syncthreads();
  float ym = yg[d];
  float yc = yg[D_ + d];
  float dprev = 0.0f;
  for (int i = 1; i <= 126; ++i) {
    float yp = yg[(i + 1) * D_ + d];
    float rhs = 6.0f * ((yp - yc) * invh[i] - (yc - ym) * invh[i - 1]);
    float hm = tl[i] - tl[i - 1];
    dprev = (rhs - hm * dprev) * invm[i];
    M[i * D_ + d] = dprev;      // temp: dp[i]
    ym = yc; yc = yp;
  }
  float x = M[126 * D_ + d];    // M[126] = dp[126] already final
  for (int i = 125; i >= 1; --i) {
    x = M[i * D_ + d] - cp[i] * x;
    M[i * D_ + d] = x;
  }
  M[d] = 0.0f;
  M[127 * D_ + d] = 0.0f;
}

// Per-p block: spline eval at s=xs_p*u_n, F-MLP, hden, S accumulation.
__global__ __launch_bounds__(256) void k_point(
    const float* __restrict__ t, const float* __restrict__ yg,
    const float* __restrict__ Msp,
    const float* __restrict__ W1, const float* __restrict__ b1,
    const float* __restrict__ W2, const float* __restrict__ b2,
    const float* __restrict__ Wk1, const float* __restrict__ bk1,
    float* __restrict__ S) {
  int p = blockIdx.x;
  int tid = threadIdx.x;
  __shared__ float tl[128];
  __shared__ float sn[32], an[32], bn[32], cA[32], cB[32];
  __shared__ int idn[32];
  __shared__ __align__(16) float bufA[128 * 36];  // ysT[d][36] then fy[n][128]
  __shared__ __align__(16) float h1T[256 * 36];   // h1T[c][36]
  __shared__ __align__(16) float hdl[32 * 64];    // hden[n][c]
  if (tid < 128) tl[tid] = t[tid];
  __syncthreads();
  float xp = (p < T_) ? tl[p] : 0.5f * (tl[p - T_] + tl[p - T_ + 1]);
  if (tid < 32) {
    int n = tid;
    float u = (float)n * (1.0f / 31.0f);
    float q = xp * u;
    float qc = fminf(fmaxf(q, tl[0]), tl[127]);
    int i = (int)floorf(qc * 127.0f);
    i = max(0, min(126, i));
    while (i > 0 && qc < tl[i]) --i;
    while (i < 126 && qc >= tl[i + 1]) ++i;
    float h = tl[i + 1] - tl[i];
    float a = (tl[i + 1] - qc) / h, b = (qc - tl[i]) / h;
    sn[n] = q; idn[n] = i; an[n] = a; bn[n] = b;
    float h26 = h * h * (1.0f / 6.0f);
    cA[n] = (a * a * a - a) * h26;
    cB[n] = (b * b * b - b) * h26;
  }
  __syncthreads();
  // phase 1: ysT[d][n]
  {
    int d = tid & 127, half = tid >> 7;
    #pragma unroll
    for (int pass = 0; pass < 16; ++pass) {
      int n = pass * 2 + half;
      int i = idn[n];
      bufA[d * 36 + n] = an[n] * yg[i * 128 + d] + bn[n] * yg[(i + 1) * 128 + d]
                       + cA[n] * Msp[i * 128 + d] + cB[n] * Msp[(i + 1) * 128 + d];
    }
  }
  // hden[n][c] = tanh(xp*Wk1[0,c] + s_n*Wk1[1,c] + bk1[c])
  #pragma unroll
  for (int k = 0; k < 8; ++k) {
    int nc = k * 256 + tid;
    int n = nc >> 6, c = nc & 63;
    hdl[nc] = tanhf(fmaf(xp, Wk1[c], fmaf(sn[n], Wk1[64 + c], bk1[c])));
  }
  __syncthreads();
  // phase 2: h1T[hc][n] = tanh(ys @ W1 + b1); thread: 4 hc cols x 8 n rows
  {
    int hcb = (tid & 63) * 4;
    int nb = (tid >> 6) * 8;
    float acc[4][8];
    float4 b14 = *(const float4*)&b1[hcb];
    float bb[4] = {b14.x, b14.y, b14.z, b14.w};
    #pragma unroll
    for (int c = 0; c < 4; ++c)
      #pragma unroll
      for (int k = 0; k < 8; ++k) acc[c][k] = bb[c];
    for (int d = 0; d < 128; ++d) {
      float4 w4 = *(const float4*)&W1[d * 256 + hcb];
      float4 ya = *(const float4*)&bufA[d * 36 + nb];
      float4 yb = *(const float4*)&bufA[d * 36 + nb + 4];
      float w_[4] = {w4.x, w4.y, w4.z, w4.w};
      float y_[8] = {ya.x, ya.y, ya.z, ya.w, yb.x, yb.y, yb.z, yb.w};
      #pragma unroll
      for (int c = 0; c < 4; ++c)
        #pragma unroll
        for (int k = 0; k < 8; ++k)
          acc[c][k] = fmaf(w_[c], y_[k], acc[c][k]);
    }
    #pragma unroll
    for (int c = 0; c < 4; ++c)
      #pragma unroll
      for (int k = 0; k < 8; ++k)
        h1T[(hcb + c) * 36 + nb + k] = tanhf(acc[c][k]);
  }
  __syncthreads();
  // phase 3: fy[n][j] = tanh_h1 @ W2 + b2; thread: 4 n rows x 4 j cols
  {
    int jb = (tid & 31) * 4;
    int nb = (tid >> 5) * 4;
    float acc[4][4];
    float4 b24 = *(const float4*)&b2[jb];
    float bj[4] = {b24.x, b24.y, b24.z, b24.w};
    #pragma unroll
    for (int nn = 0; nn < 4; ++nn)
      #pragma unroll
      for (int jj = 0; jj < 4; ++jj) acc[nn][jj] = bj[jj];
    for (int c = 0; c < 256; ++c) {
      float4 w4 = *(const float4*)&W2[c * 128 + jb];
      float4 h4 = *(const float4*)&h1T[c * 36 + nb];
      float w_[4] = {w4.x, w4.y, w4.z, w4.w};
      float h_[4] = {h4.x, h4.y, h4.z, h4.w};
      #pragma unroll
      for (int nn = 0; nn < 4; ++nn)
        #pragma unroll
        for (int jj = 0; jj < 4; ++jj)
          acc[nn][jj] = fmaf(h_[nn], w_[jj], acc[nn][jj]);
    }
    #pragma unroll
    for (int nn = 0; nn < 4; ++nn)
      *(float4*)&bufA[(nb + nn) * 128 + jb] =
          make_float4(acc[nn][0], acc[nn][1], acc[nn][2], acc[nn][3]);
  }
  __syncthreads();
  // phase 4: S[c][j] = sum_n wq_n * hden[n][c] * fy[n][j]; plus fybar row
  {
    int jb = (tid & 31) * 4;
    int ch = tid >> 5;  // c in [ch*8, ch*8+8)
    float acc[8][4];
    #pragma unroll
    for (int c = 0; c < 8; ++c)
      #pragma unroll
      for (int jj = 0; jj < 4; ++jj) acc[c][jj] = 0.0f;
    float fyb[4] = {0.f, 0.f, 0.f, 0.f};
    for (int n = 0; n < 32; ++n) {
      float wq = (n == 0 || n == 31) ? 0.5f : 1.0f;
      float4 f4 = *(const float4*)&bufA[n * 128 + jb];
      float f_[4] = {f4.x * wq, f4.y * wq, f4.z * wq, f4.w * wq};
      if (ch == 0) {
        fyb[0] += f_[0]; fyb[1] += f_[1]; fyb[2] += f_[2]; fyb[3] += f_[3];
      }
      float4 hA = *(const float4*)&hdl[n * 64 + ch * 8];
      float4 hB = *(const float4*)&hdl[n * 64 + ch * 8 + 4];
      float h_[8] = {hA.x, hA.y, hA.z, hA.w, hB.x, hB.y, hB.z, hB.w};
      #pragma unroll
      for (int c = 0; c < 8; ++c)
        #pragma unroll
        for (int jj = 0; jj < 4; ++jj)
          acc[c][jj] = fmaf(h_[c], f_[jj], acc[c][jj]);
    }
    float* sp = S + p * SROW;
    #pragma unroll
    for (int c = 0; c < 8; ++c)
      *(float4*)&sp[(ch * 8 + c) * 128 + jb] =
          make_float4(acc[c][0], acc[c][1], acc[c][2], acc[c][3]);
    if (ch == 0)
      *(float4*)&sp[8192 + jb] = make_float4(fyb[0], fyb[1], fyb[2], fyb[3]);
  }
}

// partial[cc][p][i] = sum over c in chunk cc of sum_j S[p][c][j]*WT[c][j][i]
__global__ __launch_bounds__(256) void k_gemm(const float* __restrict__ S,
                                              const float* __restrict__ WT,
                                              float* __restrict__ part) {
  int cc = blockIdx.x;   // 0..32
  int pt = blockIdx.y;   // 0..16
  int c0 = cc * 2;
  int nc = (c0 + 1 < 65) ? 2 : 1;
  int p0 = pt * 15;
  int tid = threadIdx.x;
  __shared__ __align__(16) float Sl[2 * 1920];  // [cl][pl][j]
  for (int idx = tid; idx < nc * 1920; idx += 256) {
    int cl = idx / 1920, rem = idx % 1920;
    Sl[idx] = S[(p0 + (rem >> 7)) * SROW + (c0 + cl) * 128 + (rem & 127)];
  }
  __syncthreads();
  int i = (tid & 31) * 4;
  int grp = tid >> 5;  // p = p0+grp and p0+grp+8 (if grp<7)
  float a0[4] = {0.f, 0.f, 0.f, 0.f};
  float a1[4] = {0.f, 0.f, 0.f, 0.f};
  for (int cl = 0; cl < nc; ++cl) {
    const float* wt = WT + (c0 + cl) * 16384 + i;
    const float* s0p = Sl + cl * 1920 + grp * 128;
    for (int j4 = 0; j4 < 32; ++j4) {
      float4 sa4 = *(const float4*)&s0p[j4 * 4];
      float4 sb4 = (grp < 7) ? *(const float4*)&s0p[1024 + j4 * 4]
                             : make_float4(0.f, 0.f, 0.f, 0.f);
      float sa_[4] = {sa4.x, sa4.y, sa4.z, sa4.w};
      float sb_[4] = {sb4.x, sb4.y, sb4.z, sb4.w};
      #pragma unroll
      for (int jj = 0; jj < 4; ++jj) {
        float4 w = *(const float4*)&wt[(j4 * 4 + jj) * 128];
        a0[0] = fmaf(w.x, sa_[jj], a0[0]);
        a0[1] = fmaf(w.y, sa_[jj], a0[1]);
        a0[2] = fmaf(w.z, sa_[jj], a0[2]);
        a0[3] = fmaf(w.w, sa_[jj], a0[3]);
        a1[0] = fmaf(w.x, sb_[jj], a1[0]);
        a1[1] = fmaf(w.y, sb_[jj], a1[1]);
        a1[2] = fmaf(w.z, sb_[jj], a1[2]);
        a1[3] = fmaf(w.w, sb_[jj], a1[3]);
      }
    }
  }
  *(float4*)&part[cc * GSZ + (p0 + grp) * 128 + i] =
      make_float4(a0[0], a0[1], a0[2], a0[3]);
  if (grp < 7)
    *(float4*)&part[cc * GSZ + (p0 + grp + 8) * 128 + i] =
        make_float4(a1[0], a1[1], a1[2], a1[3]);
}

__global__ __launch_bounds__(256) void k_reduce(const float* __restrict__ part,
                                                const float* __restrict__ t,
                                                float* __restrict__ g) {
  int idx = blockIdx.x * 256 + threadIdx.x;
  if (idx >= GSZ) return;
  float s = 0.f;
  #pragma unroll
  for (int cc = 0; cc < NCH; ++cc) s += part[cc * GSZ + idx];
  int p = idx >> 7;
  float xp = (p < T_) ? t[p] : 0.5f * (t[p - T_] + t[p - T_ + 1]);
  g[idx] = s * (xp * (1.0f / 31.0f));
}

// Simpson increments + cumulative sum -> new yg (and d_out on last iter)
__global__ __launch_bounds__(128) void k_final(const float* __restrict__ t,
                                               const float* __restrict__ z0,
                                               const float* __restrict__ g,
                                               float* __restrict__ yg,
                                               float* __restrict__ out, int wout) {
  int d = threadIdx.x;
  float acc = z0[d];
  yg[d] = acc;
  if (wout) out[d] = acc;
  for (int k = 0; k < 127; ++k) {
    float h = t[k + 1] - t[k];
    float inc = h * (1.0f / 6.0f) *
        (g[k * 128 + d] + 4.0f * g[(T_ + k) * 128 + d] + g[(k + 1) * 128 + d]);
    acc += inc;
    yg[(k + 1) * 128 + d] = acc;
    if (wout) out[(k + 1) * 128 + d] = acc;
  }
}

extern "C" void kernel_launch(void* const* d_in, const int* in_sizes, int n_in,
                              void* d_out, int out_size, void* d_ws, size_t ws_size,
                              hipStream_t stream) {
  const float* z0  = (const float*)d_in[0];
  const float* t   = (const float*)d_in[1];
  const float* W1  = (const float*)d_in[2];
  const float* b1  = (const float*)d_in[3];
  const float* W2  = (const float*)d_in[4];
  const float* b2  = (const float*)d_in[5];
  const float* Wk1 = (const float*)d_in[6];
  const float* bk1 = (const float*)d_in[7];
  const float* Wk2 = (const float*)d_in[8];
  const float* bk2 = (const float*)d_in[9];
  float* out = (float*)d_out;
  float* ws  = (float*)d_ws;

  float* yg   = ws + OFF_YG;
  float* M    = ws + OFF_M;
  float* WT   = ws + OFF_WT;
  float* S    = ws + OFF_S;
  float* part = ws + OFF_PART;
  float* g    = ws + OFF_G;

  k_init<<<dim3(64), dim3(256), 0, stream>>>(z0, yg);
  k_transpose<<<dim3(65), dim3(256), 0, stream>>>(Wk2, bk2, WT);
  for (int it = 0; it < 3; ++it) {
    k_spline<<<dim3(1), dim3(128), 0, stream>>>(t, yg, M);
    k_point<<<dim3(255), dim3(256), 0, stream>>>(t, yg, M, W1, b1, W2, b2, Wk1, bk1, S);
    k_gemm<<<dim3(NCH, 17), dim3(256), 0, stream>>>(S, WT, part);
    k_reduce<<<dim3(128), dim3(256), 0, stream>>>(part, t, g);
    k_final<<<dim3(1), dim3(128), 0, stream>>>(t, z0, g, yg, out, (it == 2) ? 1 : 0);
  }
}

// Round 2
// 342.341 us; speedup vs baseline: 3.6010x; 3.6010x over previous
//
#include <hip/hip_runtime.h>

// Problem constants
#define D_  128
#define T_  128
#define N_  32
#define H_  256
#define HK_ 64
#define P_  255           // 2T-1 evaluation points (t grid + midpoints)
#define SROW 8320         // 65*128: S row stride (64 hden rows + 1 fybar row)
#define NCH  33           // c-chunks of 2 over 65 rows
#define GSZ  32640        // 255*128

// workspace offsets (in floats)
#define OFF_YG   0                 // yg: T*D
#define OFF_M    16384             // spline M: T*D
#define OFF_WT   32768             // WT[c][j][i], c in 0..64 (row 64 = bk2): 65*16384
#define OFF_S    1097728           // S[p][c][j]: 255*8320
#define OFF_PART 3219328           // partial[cc][p][i]: 33*32640
#define OFF_G    4296448           // g[p][i]: 32640
#define OFF_COEF 4329088           // cp[128] | invm[128] | invh[128]
// total = 4329472 floats = ~16.5 MiB of d_ws required

__global__ __launch_bounds__(256) void k_init(const float* __restrict__ z0,
                                              float* __restrict__ yg) {
  int idx = blockIdx.x * 256 + threadIdx.x;
  if (idx < T_ * D_) yg[idx] = z0[idx & (D_ - 1)];
}

// One-time Thomas coefficients (iteration-invariant, depend only on t).
__global__ __launch_bounds__(128) void k_precoef(const float* __restrict__ t,
                                                 float* __restrict__ coef) {
  int d = threadIdx.x;
  if (d < 127) coef[256 + d] = 1.0f / (t[d + 1] - t[d]);   // invh[d]
  if (d == 0) {
    float cprev = 0.0f;
    float tm = t[0], tc = t[1];
    for (int i = 1; i <= 126; ++i) {
      float tp = t[i + 1];
      float hm = tc - tm, hi = tp - tc;
      float m = 2.0f * (hm + hi) - hm * cprev;
      float im = 1.0f / m;
      coef[128 + i] = im;       // invm[i]
      cprev = hi * im;
      coef[i] = cprev;          // cp[i]
      tm = tc; tc = tp;
    }
  }
}

// WT[c][j][i] = Wrow_c[i*128 + j], Wrow_c = Wk2 + c*16384 (c<64) or bk2 (c==64)
__global__ __launch_bounds__(256) void k_transpose(const float* __restrict__ Wk2,
                                                   const float* __restrict__ bk2,
                                                   float* __restrict__ WT) {
  int c = blockIdx.x;
  const float* src = (c < 64) ? (Wk2 + c * 16384) : bk2;
  __shared__ float tile[16384];
  #pragma unroll 8
  for (int k = 0; k < 64; ++k) {
    int idx = k * 256 + threadIdx.x;
    int i = idx >> 7, j = idx & 127;
    tile[j * 128 + (i ^ (j & 31))] = src[idx];
  }
  __syncthreads();
  float* dst = WT + c * 16384;
  #pragma unroll 8
  for (int k = 0; k < 64; ++k) {
    int idx = k * 256 + threadIdx.x;
    int jj = idx >> 7, ii = idx & 127;
    dst[idx] = tile[jj * 128 + (ii ^ (jj & 31))];
  }
}

// Natural cubic spline second-derivatives M (T,D), Thomas algorithm.
// dp staged in LDS (rows 1..125; row 126 kept in a register).
__global__ __launch_bounds__(128) void k_spline(const float* __restrict__ t,
                                                const float* __restrict__ coef,
                                                const float* __restrict__ yg,
                                                float* __restrict__ M) {
  int d = threadIdx.x;
  __shared__ float dp[125 * 128];   // 64000 B
  __shared__ float cp[126];
  __shared__ float im[127];
  __shared__ float ivh[127];
  if (d < 126) cp[d] = coef[d];
  if (d < 127) { im[d] = coef[128 + d]; ivh[d] = coef[256 + d]; }
  __syncthreads();
  float ym = yg[d], yc = yg[128 + d];
  float tm = t[0], tc = t[1];
  float dprev = 0.0f;
  float dp126 = 0.0f;
  for (int i = 1; i <= 126; ++i) {
    float tp = t[i + 1];
    float yp = yg[(i + 1) * 128 + d];
    float rhs = 6.0f * ((yp - yc) * ivh[i] - (yc - ym) * ivh[i - 1]);
    float hm = tc - tm;
    dprev = (rhs - hm * dprev) * im[i];
    if (i < 126) dp[(i - 1) * 128 + d] = dprev; else dp126 = dprev;
    ym = yc; yc = yp; tm = tc; tc = tp;
  }
  float x = dp126;
  M[126 * 128 + d] = x;
  for (int i = 125; i >= 1; --i) {
    x = dp[(i - 1) * 128 + d] - cp[i] * x;
    M[i * 128 + d] = x;
  }
  M[d] = 0.0f;
  M[127 * 128 + d] = 0.0f;
}

// Per-p block: spline eval at s=xs_p*u_n, F-MLP, hden, S accumulation.
__global__ __launch_bounds__(256) void k_point(
    const float* __restrict__ t, const float* __restrict__ yg,
    const float* __restrict__ Msp,
    const float* __restrict__ W1, const float* __restrict__ b1,
    const float* __restrict__ W2, const float* __restrict__ b2,
    const float* __restrict__ Wk1, const float* __restrict__ bk1,
    float* __restrict__ S) {
  int p = blockIdx.x;
  int tid = threadIdx.x;
  __shared__ float tl[128];
  __shared__ float sn[32], an[32], bn[32], cA[32], cB[32];
  __shared__ int idn[32];
  __shared__ __align__(16) float bufA[128 * 36];  // ysT[d][36] then fy[n][128]
  __shared__ __align__(16) float h1T[256 * 36];   // h1T[c][36]
  __shared__ __align__(16) float hdl[32 * 64];    // hden[n][c]
  if (tid < 128) tl[tid] = t[tid];
  __syncthreads();
  float xp = (p < T_) ? tl[p] : 0.5f * (tl[p - T_] + tl[p - T_ + 1]);
  if (tid < 32) {
    int n = tid;
    float u = (float)n * (1.0f / 31.0f);
    float q = xp * u;
    float qc = fminf(fmaxf(q, tl[0]), tl[127]);
    int i = (int)floorf(qc * 127.0f);
    i = max(0, min(126, i));
    while (i > 0 && qc < tl[i]) --i;
    while (i < 126 && qc >= tl[i + 1]) ++i;
    float h = tl[i + 1] - tl[i];
    float a = (tl[i + 1] - qc) / h, b = (qc - tl[i]) / h;
    sn[n] = q; idn[n] = i; an[n] = a; bn[n] = b;
    float h26 = h * h * (1.0f / 6.0f);
    cA[n] = (a * a * a - a) * h26;
    cB[n] = (b * b * b - b) * h26;
  }
  __syncthreads();
  // phase 1: ysT[d][n]
  {
    int d = tid & 127, half = tid >> 7;
    #pragma unroll
    for (int pass = 0; pass < 16; ++pass) {
      int n = pass * 2 + half;
      int i = idn[n];
      bufA[d * 36 + n] = an[n] * yg[i * 128 + d] + bn[n] * yg[(i + 1) * 128 + d]
                       + cA[n] * Msp[i * 128 + d] + cB[n] * Msp[(i + 1) * 128 + d];
    }
  }
  // hden[n][c] = tanh(xp*Wk1[0,c] + s_n*Wk1[1,c] + bk1[c])
  #pragma unroll
  for (int k = 0; k < 8; ++k) {
    int nc = k * 256 + tid;
    int n = nc >> 6, c = nc & 63;
    hdl[nc] = tanhf(fmaf(xp, Wk1[c], fmaf(sn[n], Wk1[64 + c], bk1[c])));
  }
  __syncthreads();
  // phase 2: h1T[hc][n] = tanh(ys @ W1 + b1); thread: 4 hc cols x 8 n rows
  {
    int hcb = (tid & 63) * 4;
    int nb = (tid >> 6) * 8;
    float acc[4][8];
    float4 b14 = *(const float4*)&b1[hcb];
    float bb[4] = {b14.x, b14.y, b14.z, b14.w};
    #pragma unroll
    for (int c = 0; c < 4; ++c)
      #pragma unroll
      for (int k = 0; k < 8; ++k) acc[c][k] = bb[c];
    for (int d = 0; d < 128; ++d) {
      float4 w4 = *(const float4*)&W1[d * 256 + hcb];
      float4 ya = *(const float4*)&bufA[d * 36 + nb];
      float4 yb = *(const float4*)&bufA[d * 36 + nb + 4];
      float w_[4] = {w4.x, w4.y, w4.z, w4.w};
      float y_[8] = {ya.x, ya.y, ya.z, ya.w, yb.x, yb.y, yb.z, yb.w};
      #pragma unroll
      for (int c = 0; c < 4; ++c)
        #pragma unroll
        for (int k = 0; k < 8; ++k)
          acc[c][k] = fmaf(w_[c], y_[k], acc[c][k]);
    }
    #pragma unroll
    for (int c = 0; c < 4; ++c)
      #pragma unroll
      for (int k = 0; k < 8; ++k)
        h1T[(hcb + c) * 36 + nb + k] = tanhf(acc[c][k]);
  }
  __syncthreads();
  // phase 3: fy[n][j] = tanh_h1 @ W2 + b2; thread: 4 n rows x 4 j cols
  {
    int jb = (tid & 31) * 4;
    int nb = (tid >> 5) * 4;
    float acc[4][4];
    float4 b24 = *(const float4*)&b2[jb];
    float bj[4] = {b24.x, b24.y, b24.z, b24.w};
    #pragma unroll
    for (int nn = 0; nn < 4; ++nn)
      #pragma unroll
      for (int jj = 0; jj < 4; ++jj) acc[nn][jj] = bj[jj];
    for (int c = 0; c < 256; ++c) {
      float4 w4 = *(const float4*)&W2[c * 128 + jb];
      float4 h4 = *(const float4*)&h1T[c * 36 + nb];
      float w_[4] = {w4.x, w4.y, w4.z, w4.w};
      float h_[4] = {h4.x, h4.y, h4.z, h4.w};
      #pragma unroll
      for (int nn = 0; nn < 4; ++nn)
        #pragma unroll
        for (int jj = 0; jj < 4; ++jj)
          acc[nn][jj] = fmaf(h_[nn], w_[jj], acc[nn][jj]);
    }
    #pragma unroll
    for (int nn = 0; nn < 4; ++nn)
      *(float4*)&bufA[(nb + nn) * 128 + jb] =
          make_float4(acc[nn][0], acc[nn][1], acc[nn][2], acc[nn][3]);
  }
  __syncthreads();
  // phase 4: S[c][j] = sum_n wq_n * hden[n][c] * fy[n][j]; plus fybar row
  {
    int jb = (tid & 31) * 4;
    int ch = tid >> 5;  // c in [ch*8, ch*8+8)
    float acc[8][4];
    #pragma unroll
    for (int c = 0; c < 8; ++c)
      #pragma unroll
      for (int jj = 0; jj < 4; ++jj) acc[c][jj] = 0.0f;
    float fyb[4] = {0.f, 0.f, 0.f, 0.f};
    for (int n = 0; n < 32; ++n) {
      float wq = (n == 0 || n == 31) ? 0.5f : 1.0f;
      float4 f4 = *(const float4*)&bufA[n * 128 + jb];
      float f_[4] = {f4.x * wq, f4.y * wq, f4.z * wq, f4.w * wq};
      if (ch == 0) {
        fyb[0] += f_[0]; fyb[1] += f_[1]; fyb[2] += f_[2]; fyb[3] += f_[3];
      }
      float4 hA = *(const float4*)&hdl[n * 64 + ch * 8];
      float4 hB = *(const float4*)&hdl[n * 64 + ch * 8 + 4];
      float h_[8] = {hA.x, hA.y, hA.z, hA.w, hB.x, hB.y, hB.z, hB.w};
      #pragma unroll
      for (int c = 0; c < 8; ++c)
        #pragma unroll
        for (int jj = 0; jj < 4; ++jj)
          acc[c][jj] = fmaf(h_[c], f_[jj], acc[c][jj]);
    }
    float* sp = S + p * SROW;
    #pragma unroll
    for (int c = 0; c < 8; ++c)
      *(float4*)&sp[(ch * 8 + c) * 128 + jb] =
          make_float4(acc[c][0], acc[c][1], acc[c][2], acc[c][3]);
    if (ch == 0)
      *(float4*)&sp[8192 + jb] = make_float4(fyb[0], fyb[1], fyb[2], fyb[3]);
  }
}

// partial[cc][p][i] = sum over k in c-chunk cc of S[p][k]*WT[k][i]
// Register-blocked: LDS broadcast of S, one float4 WT stream per lane.
__global__ __launch_bounds__(256) void k_gemm(const float* __restrict__ S,
                                              const float* __restrict__ WT,
                                              float* __restrict__ part) {
  int pt = blockIdx.x;   // 0..16  (15 p each)
  int cc = blockIdx.y;   // 0..32  (2 c each, last has 1)
  int c0 = cc * 2;
  int nk = (c0 + 1 < 65) ? 256 : 128;
  int p0 = pt * 15;
  int tid = threadIdx.x;
  __shared__ float Sl[15 * 256];
  for (int idx = tid; idx < 15 * 256; idx += 256) {
    int pl = idx >> 8, kk = idx & 255;
    Sl[idx] = (kk < nk) ? S[(p0 + pl) * SROW + c0 * 128 + kk] : 0.0f;
  }
  __syncthreads();
  int i4 = (tid & 31) * 4;
  int grp = tid >> 5;                       // rows p0+grp and p0+grp+8
  int grp2 = (grp < 7) ? grp + 8 : grp;
  const float* wb = WT + c0 * 16384 + i4;
  float a0[4] = {0.f, 0.f, 0.f, 0.f};
  float a1[4] = {0.f, 0.f, 0.f, 0.f};
  #pragma unroll 8
  for (int kk = 0; kk < nk; ++kk) {
    float4 w = *(const float4*)&wb[kk * 128];
    float s0 = Sl[grp * 256 + kk];
    float s1 = Sl[grp2 * 256 + kk];
    a0[0] = fmaf(w.x, s0, a0[0]); a0[1] = fmaf(w.y, s0, a0[1]);
    a0[2] = fmaf(w.z, s0, a0[2]); a0[3] = fmaf(w.w, s0, a0[3]);
    a1[0] = fmaf(w.x, s1, a1[0]); a1[1] = fmaf(w.y, s1, a1[1]);
    a1[2] = fmaf(w.z, s1, a1[2]); a1[3] = fmaf(w.w, s1, a1[3]);
  }
  *(float4*)&part[cc * GSZ + (p0 + grp) * 128 + i4] =
      make_float4(a0[0], a0[1], a0[2], a0[3]);
  if (grp < 7)
    *(float4*)&part[cc * GSZ + (p0 + grp + 8) * 128 + i4] =
        make_float4(a1[0], a1[1], a1[2], a1[3]);
}

__global__ __launch_bounds__(256) void k_reduce(const float* __restrict__ part,
                                                const float* __restrict__ t,
                                                float* __restrict__ g) {
  int idx = blockIdx.x * 256 + threadIdx.x;
  if (idx >= GSZ) return;
  float s = 0.f;
  #pragma unroll
  for (int cc = 0; cc < NCH; ++cc) s += part[cc * GSZ + idx];
  int p = idx >> 7;
  float xp = (p < T_) ? t[p] : 0.5f * (t[p - T_] + t[p - T_ + 1]);
  g[idx] = s * (xp * (1.0f / 31.0f));
}

// Simpson increments (parallel, LDS) + cumulative sum -> new yg (+ d_out)
__global__ __launch_bounds__(256) void k_final(const float* __restrict__ t,
                                               const float* __restrict__ z0,
                                               const float* __restrict__ g,
                                               float* __restrict__ yg,
                                               float* __restrict__ out, int wout) {
  __shared__ float inc[127 * 128];   // 65024 B
  int tid = threadIdx.x;
  for (int idx = tid; idx < 127 * 128; idx += 256) {
    int k = idx >> 7, d = idx & 127;
    float h = t[k + 1] - t[k];
    inc[idx] = h * (1.0f / 6.0f) *
        (g[k * 128 + d] + 4.0f * g[(T_ + k) * 128 + d] + g[(k + 1) * 128 + d]);
  }
  __syncthreads();
  if (tid < 128) {
    int d = tid;
    float acc = z0[d];
    yg[d] = acc;
    if (wout) out[d] = acc;
    for (int k = 0; k < 127; ++k) {
      acc += inc[k * 128 + d];
      yg[(k + 1) * 128 + d] = acc;
      if (wout) out[(k + 1) * 128 + d] = acc;
    }
  }
}

extern "C" void kernel_launch(void* const* d_in, const int* in_sizes, int n_in,
                              void* d_out, int out_size, void* d_ws, size_t ws_size,
                              hipStream_t stream) {
  const float* z0  = (const float*)d_in[0];
  const float* t   = (const float*)d_in[1];
  const float* W1  = (const float*)d_in[2];
  const float* b1  = (const float*)d_in[3];
  const float* W2  = (const float*)d_in[4];
  const float* b2  = (const float*)d_in[5];
  const float* Wk1 = (const float*)d_in[6];
  const float* bk1 = (const float*)d_in[7];
  const float* Wk2 = (const float*)d_in[8];
  const float* bk2 = (const float*)d_in[9];
  float* out = (float*)d_out;
  float* ws  = (float*)d_ws;

  float* yg   = ws + OFF_YG;
  float* M    = ws + OFF_M;
  float* WT   = ws + OFF_WT;
  float* S    = ws + OFF_S;
  float* part = ws + OFF_PART;
  float* g    = ws + OFF_G;
  float* coef = ws + OFF_COEF;

  k_init<<<dim3(64), dim3(256), 0, stream>>>(z0, yg);
  k_precoef<<<dim3(1), dim3(128), 0, stream>>>(t, coef);
  k_transpose<<<dim3(65), dim3(256), 0, stream>>>(Wk2, bk2, WT);
  for (int it = 0; it < 3; ++it) {
    k_spline<<<dim3(1), dim3(128), 0, stream>>>(t, coef, yg, M);
    k_point<<<dim3(255), dim3(256), 0, stream>>>(t, yg, M, W1, b1, W2, b2, Wk1, bk1, S);
    k_gemm<<<dim3(17, NCH), dim3(256), 0, stream>>>(S, WT, part);
    k_reduce<<<dim3(128), dim3(256), 0, stream>>>(part, t, g);
    k_final<<<dim3(1), dim3(256), 0, stream>>>(t, z0, g, yg, out, (it == 2) ? 1 : 0);
  }
}

// Round 3
// 342.138 us; speedup vs baseline: 3.6032x; 1.0006x over previous
//
#include <hip/hip_runtime.h>

// Problem constants
#define D_  128
#define T_  128
#define N_  32
#define H_  256
#define HK_ 64
#define P_  255           // 2T-1 evaluation points (t grid + midpoints)
#define SROW 8320         // 65*128: S row stride (64 hden rows + 1 fybar row)
#define NCH  33           // c-chunks of 2 over 65 rows
#define GSZ  32640        // 255*128

// workspace offsets (in floats)
#define OFF_YG   0                 // yg: T*D
#define OFF_M    16384             // spline M: T*D
#define OFF_WT   32768             // WT[c][j][i], c in 0..64 (row 64 = bk2): 65*16384
#define OFF_S    1097728           // S[p][c][j]: 255*8320
#define OFF_PART 3219328           // partial[cc][p][i]: 33*32640
#define OFF_G    4296448           // g[p][i]: 32640
#define OFF_COEF 4329088           // cp[128] | invm[128] | invh[128] | h[128]
// total = 4329600 floats = ~16.5 MiB of d_ws required

__global__ __launch_bounds__(256) void k_init(const float* __restrict__ z0,
                                              float* __restrict__ yg) {
  int idx = blockIdx.x * 256 + threadIdx.x;
  if (idx < T_ * D_) yg[idx] = z0[idx & (D_ - 1)];
}

// One-time Thomas coefficients (iteration-invariant, depend only on t).
__global__ __launch_bounds__(128) void k_precoef(const float* __restrict__ t,
                                                 float* __restrict__ coef) {
  int d = threadIdx.x;
  if (d < 127) {
    float h = t[d + 1] - t[d];
    coef[256 + d] = 1.0f / h;   // invh[d]
    coef[384 + d] = h;          // h[d]
  }
  if (d == 0) {
    float cprev = 0.0f;
    float tm = t[0], tc = t[1];
    for (int i = 1; i <= 126; ++i) {
      float tp = t[i + 1];
      float hm = tc - tm, hi = tp - tc;
      float m = 2.0f * (hm + hi) - hm * cprev;
      float im = 1.0f / m;
      coef[128 + i] = im;       // invm[i]
      cprev = hi * im;
      coef[i] = cprev;          // cp[i]
      tm = tc; tc = tp;
    }
  }
}

// WT[c][j][i] = Wrow_c[i*128 + j], Wrow_c = Wk2 + c*16384 (c<64) or bk2 (c==64)
__global__ __launch_bounds__(256) void k_transpose(const float* __restrict__ Wk2,
                                                   const float* __restrict__ bk2,
                                                   float* __restrict__ WT) {
  int c = blockIdx.x;
  const float* src = (c < 64) ? (Wk2 + c * 16384) : bk2;
  __shared__ float tile[16384];
  #pragma unroll 8
  for (int k = 0; k < 64; ++k) {
    int idx = k * 256 + threadIdx.x;
    int i = idx >> 7, j = idx & 127;
    tile[j * 128 + (i ^ (j & 31))] = src[idx];
  }
  __syncthreads();
  float* dst = WT + c * 16384;
  #pragma unroll 8
  for (int k = 0; k < 64; ++k) {
    int idx = k * 256 + threadIdx.x;
    int jj = idx >> 7, ii = idx & 127;
    dst[idx] = tile[jj * 128 + (ii ^ (jj & 31))];
  }
}

// Natural cubic spline second-derivatives M (T,D), Thomas algorithm.
// yg staged to LDS; dp overwrites freed yg rows. Columns are thread-private
// so no syncs are needed after staging.
__global__ __launch_bounds__(128) void k_spline(const float* __restrict__ coef,
                                                const float* __restrict__ yg,
                                                float* __restrict__ M) {
  __shared__ float buf[128 * 128];   // exactly 64 KiB
  int d = threadIdx.x;
  {
    const float4* src = (const float4*)yg;
    float4* dst = (float4*)buf;
    #pragma unroll
    for (int k = 0; k < 32; ++k) dst[k * 128 + d] = src[k * 128 + d];
  }
  __syncthreads();
  float ym = buf[d], yc = buf[128 + d];
  float dprev = 0.0f;
  #pragma unroll 4
  for (int i = 1; i <= 126; ++i) {
    float yp = buf[(i + 1) * 128 + d];
    float rhs = 6.0f * ((yp - yc) * coef[256 + i] - (yc - ym) * coef[256 + i - 1]);
    dprev = (rhs - coef[384 + i - 1] * dprev) * coef[128 + i];
    buf[(i - 1) * 128 + d] = dprev;    // dp[i] -> freed row i-1
    ym = yc; yc = yp;
  }
  float x = dprev;                      // dp[126]
  M[126 * 128 + d] = x;
  #pragma unroll 4
  for (int i = 125; i >= 1; --i) {
    x = buf[(i - 1) * 128 + d] - coef[i] * x;
    M[i * 128 + d] = x;
  }
  M[d] = 0.0f;
  M[127 * 128 + d] = 0.0f;
}

// Per-p block (512 threads): spline eval, F-MLP, hden, S accumulation.
__global__ __launch_bounds__(512) void k_point(
    const float* __restrict__ t, const float* __restrict__ yg,
    const float* __restrict__ Msp,
    const float* __restrict__ W1, const float* __restrict__ b1,
    const float* __restrict__ W2, const float* __restrict__ b2,
    const float* __restrict__ Wk1, const float* __restrict__ bk1,
    float* __restrict__ S) {
  int p = blockIdx.x;
  int tid = threadIdx.x;
  __shared__ float tl[128];
  __shared__ float sn[32], an[32], bn[32], cA[32], cB[32];
  __shared__ int idn[32];
  __shared__ __align__(16) float bufA[128 * 36];  // ysT[d][36]; then fy[n][128]
  __shared__ __align__(16) float h1T[32 * 256];   // h1[n][c]
  __shared__ __align__(16) float hdl[32 * 64];    // hden[n][c]
  if (tid < 128) tl[tid] = t[tid];
  __syncthreads();
  float xp = (p < T_) ? tl[p] : 0.5f * (tl[p - T_] + tl[p - T_ + 1]);
  if (tid < 32) {
    int n = tid;
    float u = (float)n * (1.0f / 31.0f);
    float q = xp * u;
    float qc = fminf(fmaxf(q, tl[0]), tl[127]);
    int i = (int)floorf(qc * 127.0f);
    i = max(0, min(126, i));
    while (i > 0 && qc < tl[i]) --i;
    while (i < 126 && qc >= tl[i + 1]) ++i;
    float h = tl[i + 1] - tl[i];
    float a = (tl[i + 1] - qc) / h, b = (qc - tl[i]) / h;
    sn[n] = q; idn[n] = i; an[n] = a; bn[n] = b;
    float h26 = h * h * (1.0f / 6.0f);
    cA[n] = (a * a * a - a) * h26;
    cB[n] = (b * b * b - b) * h26;
  }
  __syncthreads();
  // phase 1: ysT[d][n]
  {
    int d = tid & 127, q = tid >> 7;
    #pragma unroll
    for (int pass = 0; pass < 8; ++pass) {
      int n = pass * 4 + q;
      int i = idn[n];
      bufA[d * 36 + n] = an[n] * yg[i * 128 + d] + bn[n] * yg[(i + 1) * 128 + d]
                       + cA[n] * Msp[i * 128 + d] + cB[n] * Msp[(i + 1) * 128 + d];
    }
  }
  // hden[n][c] = tanh(xp*Wk1[0,c] + s_n*Wk1[1,c] + bk1[c])
  #pragma unroll
  for (int k = 0; k < 4; ++k) {
    int nc = k * 512 + tid;
    int n = nc >> 6, c = nc & 63;
    hdl[nc] = tanhf(fmaf(xp, Wk1[c], fmaf(sn[n], Wk1[64 + c], bk1[c])));
  }
  __syncthreads();
  // phase 2: h1[n][hc] = tanh(ys @ W1 + b1); thread: 2 hc cols x 8 n rows
  {
    int hcb = (tid & 127) * 2;
    int nb = (tid >> 7) * 8;
    float acc[2][8];
    float2 b12 = *(const float2*)&b1[hcb];
    #pragma unroll
    for (int k = 0; k < 8; ++k) { acc[0][k] = b12.x; acc[1][k] = b12.y; }
    #pragma unroll 4
    for (int d = 0; d < 128; ++d) {
      float2 w2 = *(const float2*)&W1[d * 256 + hcb];
      float4 ya = *(const float4*)&bufA[d * 36 + nb];
      float4 yb = *(const float4*)&bufA[d * 36 + nb + 4];
      float y_[8] = {ya.x, ya.y, ya.z, ya.w, yb.x, yb.y, yb.z, yb.w};
      #pragma unroll
      for (int k = 0; k < 8; ++k) {
        acc[0][k] = fmaf(w2.x, y_[k], acc[0][k]);
        acc[1][k] = fmaf(w2.y, y_[k], acc[1][k]);
      }
    }
    #pragma unroll
    for (int k = 0; k < 8; ++k) {
      float2 v = make_float2(tanhf(acc[0][k]), tanhf(acc[1][k]));
      *(float2*)&h1T[(nb + k) * 256 + hcb] = v;
    }
  }
  __syncthreads();
  // phase 3: fy[n][j] = wq_n*(h1 @ W2 + b2); thread: 2 n rows x 4 j cols
  {
    int jb = (tid & 31) * 4;
    int ng = tid >> 5;            // 16 groups x 2 rows
    int n0 = ng * 2, n1 = n0 + 1;
    float acc[2][4];
    float4 b24 = *(const float4*)&b2[jb];
    acc[0][0] = b24.x; acc[0][1] = b24.y; acc[0][2] = b24.z; acc[0][3] = b24.w;
    acc[1][0] = b24.x; acc[1][1] = b24.y; acc[1][2] = b24.z; acc[1][3] = b24.w;
    #pragma unroll 4
    for (int c = 0; c < 256; ++c) {
      float4 w4 = *(const float4*)&W2[c * 128 + jb];
      float h0 = h1T[n0 * 256 + c];
      float h1 = h1T[n1 * 256 + c];
      acc[0][0] = fmaf(h0, w4.x, acc[0][0]); acc[0][1] = fmaf(h0, w4.y, acc[0][1]);
      acc[0][2] = fmaf(h0, w4.z, acc[0][2]); acc[0][3] = fmaf(h0, w4.w, acc[0][3]);
      acc[1][0] = fmaf(h1, w4.x, acc[1][0]); acc[1][1] = fmaf(h1, w4.y, acc[1][1]);
      acc[1][2] = fmaf(h1, w4.z, acc[1][2]); acc[1][3] = fmaf(h1, w4.w, acc[1][3]);
    }
    float wq0 = (n0 == 0) ? 0.5f : 1.0f;
    float wq1 = (n1 == 31) ? 0.5f : 1.0f;
    __syncthreads();   // all phase-2 reads of bufA done before overwrite
    *(float4*)&bufA[n0 * 128 + jb] =
        make_float4(acc[0][0] * wq0, acc[0][1] * wq0, acc[0][2] * wq0, acc[0][3] * wq0);
    *(float4*)&bufA[n1 * 128 + jb] =
        make_float4(acc[1][0] * wq1, acc[1][1] * wq1, acc[1][2] * wq1, acc[1][3] * wq1);
  }
  __syncthreads();
  // phase 4: S[c][j] = sum_n hden[n][c] * fyw[n][j]; fybar row = sum_n fyw
  {
    int jb = (tid & 31) * 4;
    int cg = tid >> 5;            // 16 groups x 4 c
    float acc[4][4];
    #pragma unroll
    for (int c = 0; c < 4; ++c)
      #pragma unroll
      for (int jj = 0; jj < 4; ++jj) acc[c][jj] = 0.0f;
    float fyb[4] = {0.f, 0.f, 0.f, 0.f};
    #pragma unroll 4
    for (int n = 0; n < 32; ++n) {
      float4 f4 = *(const float4*)&bufA[n * 128 + jb];
      float f_[4] = {f4.x, f4.y, f4.z, f4.w};
      if (cg == 0) {
        fyb[0] += f_[0]; fyb[1] += f_[1]; fyb[2] += f_[2]; fyb[3] += f_[3];
      }
      float4 h4 = *(const float4*)&hdl[n * 64 + cg * 4];
      float h_[4] = {h4.x, h4.y, h4.z, h4.w};
      #pragma unroll
      for (int c = 0; c < 4; ++c)
        #pragma unroll
        for (int jj = 0; jj < 4; ++jj)
          acc[c][jj] = fmaf(h_[c], f_[jj], acc[c][jj]);
    }
    float* sp = S + p * SROW;
    #pragma unroll
    for (int c = 0; c < 4; ++c)
      *(float4*)&sp[(cg * 4 + c) * 128 + jb] =
          make_float4(acc[c][0], acc[c][1], acc[c][2], acc[c][3]);
    if (cg == 0)
      *(float4*)&sp[8192 + jb] = make_float4(fyb[0], fyb[1], fyb[2], fyb[3]);
  }
}

// partial[cc][p][i] = sum over k in c-chunk cc of S[p][k]*WT[k][i]
__global__ __launch_bounds__(256) void k_gemm(const float* __restrict__ S,
                                              const float* __restrict__ WT,
                                              float* __restrict__ part) {
  int pt = blockIdx.x;   // 0..16  (15 p each)
  int cc = blockIdx.y;   // 0..32  (2 c each, last has 1)
  int c0 = cc * 2;
  int nk = (c0 + 1 < 65) ? 256 : 128;
  int p0 = pt * 15;
  int tid = threadIdx.x;
  __shared__ float Sl[15 * 256];
  for (int idx = tid; idx < 15 * 256; idx += 256) {
    int pl = idx >> 8, kk = idx & 255;
    Sl[idx] = (kk < nk) ? S[(p0 + pl) * SROW + c0 * 128 + kk] : 0.0f;
  }
  __syncthreads();
  int i4 = (tid & 31) * 4;
  int grp = tid >> 5;                       // rows p0+grp and p0+grp+8
  int grp2 = (grp < 7) ? grp + 8 : grp;
  const float* wb = WT + c0 * 16384 + i4;
  float a0[4] = {0.f, 0.f, 0.f, 0.f};
  float a1[4] = {0.f, 0.f, 0.f, 0.f};
  #pragma unroll 8
  for (int kk = 0; kk < nk; ++kk) {
    float4 w = *(const float4*)&wb[kk * 128];
    float s0 = Sl[grp * 256 + kk];
    float s1 = Sl[grp2 * 256 + kk];
    a0[0] = fmaf(w.x, s0, a0[0]); a0[1] = fmaf(w.y, s0, a0[1]);
    a0[2] = fmaf(w.z, s0, a0[2]); a0[3] = fmaf(w.w, s0, a0[3]);
    a1[0] = fmaf(w.x, s1, a1[0]); a1[1] = fmaf(w.y, s1, a1[1]);
    a1[2] = fmaf(w.z, s1, a1[2]); a1[3] = fmaf(w.w, s1, a1[3]);
  }
  *(float4*)&part[cc * GSZ + (p0 + grp) * 128 + i4] =
      make_float4(a0[0], a0[1], a0[2], a0[3]);
  if (grp < 7)
    *(float4*)&part[cc * GSZ + (p0 + grp + 8) * 128 + i4] =
        make_float4(a1[0], a1[1], a1[2], a1[3]);
}

__global__ __launch_bounds__(256) void k_reduce(const float* __restrict__ part,
                                                const float* __restrict__ t,
                                                float* __restrict__ g) {
  int idx = blockIdx.x * 256 + threadIdx.x;
  if (idx >= GSZ) return;
  float s = 0.f;
  #pragma unroll
  for (int cc = 0; cc < NCH; ++cc) s += part[cc * GSZ + idx];
  int p = idx >> 7;
  float xp = (p < T_) ? t[p] : 0.5f * (t[p - T_] + t[p - T_ + 1]);
  g[idx] = s * (xp * (1.0f / 31.0f));
}

// Simpson increments (parallel, LDS) + cumulative sum -> new yg (+ d_out)
__global__ __launch_bounds__(256) void k_final(const float* __restrict__ t,
                                               const float* __restrict__ z0,
                                               const float* __restrict__ g,
                                               float* __restrict__ yg,
                                               float* __restrict__ out, int wout) {
  __shared__ float inc[127 * 128];   // 65024 B
  int tid = threadIdx.x;
  for (int idx = tid; idx < 127 * 128; idx += 256) {
    int k = idx >> 7, d = idx & 127;
    float h = t[k + 1] - t[k];
    inc[idx] = h * (1.0f / 6.0f) *
        (g[k * 128 + d] + 4.0f * g[(T_ + k) * 128 + d] + g[(k + 1) * 128 + d]);
  }
  __syncthreads();
  if (tid < 128) {
    int d = tid;
    float acc = z0[d];
    yg[d] = acc;
    if (wout) out[d] = acc;
    #pragma unroll 4
    for (int k = 0; k < 127; ++k) {
      acc += inc[k * 128 + d];
      yg[(k + 1) * 128 + d] = acc;
      if (wout) out[(k + 1) * 128 + d] = acc;
    }
  }
}

extern "C" void kernel_launch(void* const* d_in, const int* in_sizes, int n_in,
                              void* d_out, int out_size, void* d_ws, size_t ws_size,
                              hipStream_t stream) {
  const float* z0  = (const float*)d_in[0];
  const float* t   = (const float*)d_in[1];
  const float* W1  = (const float*)d_in[2];
  const float* b1  = (const float*)d_in[3];
  const float* W2  = (const float*)d_in[4];
  const float* b2  = (const float*)d_in[5];
  const float* Wk1 = (const float*)d_in[6];
  const float* bk1 = (const float*)d_in[7];
  const float* Wk2 = (const float*)d_in[8];
  const float* bk2 = (const float*)d_in[9];
  float* out = (float*)d_out;
  float* ws  = (float*)d_ws;

  float* yg   = ws + OFF_YG;
  float* M    = ws + OFF_M;
  float* WT   = ws + OFF_WT;
  float* S    = ws + OFF_S;
  float* part = ws + OFF_PART;
  float* g    = ws + OFF_G;
  float* coef = ws + OFF_COEF;

  k_init<<<dim3(64), dim3(256), 0, stream>>>(z0, yg);
  k_precoef<<<dim3(1), dim3(128), 0, stream>>>(t, coef);
  k_transpose<<<dim3(65), dim3(256), 0, stream>>>(Wk2, bk2, WT);
  for (int it = 0; it < 3; ++it) {
    k_spline<<<dim3(1), dim3(128), 0, stream>>>(coef, yg, M);
    k_point<<<dim3(255), dim3(512), 0, stream>>>(t, yg, M, W1, b1, W2, b2, Wk1, bk1, S);
    k_gemm<<<dim3(17, NCH), dim3(256), 0, stream>>>(S, WT, part);
    k_reduce<<<dim3(128), dim3(256), 0, stream>>>(part, t, g);
    k_final<<<dim3(1), dim3(256), 0, stream>>>(t, z0, g, yg, out, (it == 2) ? 1 : 0);
  }
}

// Round 4
// 320.751 us; speedup vs baseline: 3.8434x; 1.0667x over previous
//
#include <hip/hip_runtime.h>

// Problem constants
#define D_  128
#define T_  128
#define N_  32
#define H_  256
#define HK_ 64
#define P_  255           // 2T-1 evaluation points (t grid + midpoints)
#define SROW 8320         // 65*128: S row stride (64 hden rows + 1 fybar row)
#define NCH  33           // c-chunks of 2 over 65 rows
#define GSZ  32640        // 255*128

// workspace offsets (in floats)
#define OFF_YG   0                 // yg: T*D
#define OFF_M    16384             // (unused now)
#define OFF_WT   32768             // WT[c][j][i], c in 0..64 (row 64 = bk2): 65*16384
#define OFF_S    1097728           // S[p][c][j]: 255*8320
#define OFF_PART 3219328           // partial[cc][p][i]: 33*32640
#define OFF_G    4296448           // g[p][i]: 32640
#define OFF_COEF 4329088           // cp[128] | invm[128] | invh[128] | h[128]

__device__ __forceinline__ float tanh_fast(float x) {
  // exact at +/-inf saturation; ~1e-6 abs err in between
  float e = __expf(2.0f * x);
  return 1.0f - 2.0f / (e + 1.0f);
}
__device__ __forceinline__ unsigned short f2b(float v) {   // RNE f32->bf16
  unsigned int u = __float_as_uint(v);
  u += 0x7fffu + ((u >> 16) & 1u);
  return (unsigned short)(u >> 16);
}
__device__ __forceinline__ float b2f(unsigned short h) {
  return __uint_as_float(((unsigned int)h) << 16);
}

__global__ __launch_bounds__(256) void k_init(const float* __restrict__ z0,
                                              float* __restrict__ yg) {
  int idx = blockIdx.x * 256 + threadIdx.x;
  if (idx < T_ * D_) yg[idx] = z0[idx & (D_ - 1)];
}

// One-time Thomas coefficients (iteration-invariant, depend only on t).
__global__ __launch_bounds__(128) void k_precoef(const float* __restrict__ t,
                                                 float* __restrict__ coef) {
  int d = threadIdx.x;
  if (d < 127) {
    float h = t[d + 1] - t[d];
    coef[256 + d] = 1.0f / h;   // invh[d]
    coef[384 + d] = h;          // h[d]
  }
  if (d == 0) {
    float cprev = 0.0f;
    float tm = t[0], tc = t[1];
    for (int i = 1; i <= 126; ++i) {
      float tp = t[i + 1];
      float hm = tc - tm, hi = tp - tc;
      float m = 2.0f * (hm + hi) - hm * cprev;
      float im = 1.0f / m;
      coef[128 + i] = im;       // invm[i]
      cprev = hi * im;
      coef[i] = cprev;          // cp[i]
      tm = tc; tc = tp;
    }
  }
}

// WT[c][j][i] = Wrow_c[i*128 + j], Wrow_c = Wk2 + c*16384 (c<64) or bk2 (c==64)
__global__ __launch_bounds__(256) void k_transpose(const float* __restrict__ Wk2,
                                                   const float* __restrict__ bk2,
                                                   float* __restrict__ WT) {
  int c = blockIdx.x;
  const float* src = (c < 64) ? (Wk2 + c * 16384) : bk2;
  __shared__ float tile[16384];
  #pragma unroll 8
  for (int k = 0; k < 64; ++k) {
    int idx = k * 256 + threadIdx.x;
    int i = idx >> 7, j = idx & 127;
    tile[j * 128 + (i ^ (j & 31))] = src[idx];
  }
  __syncthreads();
  float* dst = WT + c * 16384;
  #pragma unroll 8
  for (int k = 0; k < 64; ++k) {
    int idx = k * 256 + threadIdx.x;
    int jj = idx >> 7, ii = idx & 127;
    dst[idx] = tile[jj * 128 + (ii ^ (jj & 31))];
  }
}

// Per-p block (512 threads): in-block spline solve (bf16 M in LDS),
// spline eval, F-MLP (W2 LDS-staged), hden, S accumulation.
__global__ __launch_bounds__(512) void k_point(
    const float* __restrict__ t, const float* __restrict__ coef,
    const float* __restrict__ yg,
    const float* __restrict__ W1, const float* __restrict__ b1,
    const float* __restrict__ W2, const float* __restrict__ b2,
    const float* __restrict__ Wk1, const float* __restrict__ bk1,
    float* __restrict__ S) {
  int p = blockIdx.x;
  int tid = threadIdx.x;
  // R1: 32KB. phase A: bf16 M[128][128]; ph2-3: fp32 h1T[32][256]; then fy[32][128]
  __shared__ __align__(16) float R1f[8192];
  // R2: 18KB. ph1-2: ysT[d][36]; ph3: W2 chunk stage (4096 floats)
  __shared__ __align__(16) float bufA[128 * 36];
  __shared__ __align__(16) float hdl[32 * 64];    // hden[n][c]
  __shared__ float tl[128];
  __shared__ float cpS[128], imS[128], ihS[128], hS[128];
  __shared__ float sn[32], an[32], bn[32], cA[32], cB[32];
  __shared__ int idn[32];
  unsigned short* mh = (unsigned short*)R1f;      // bf16 M / dp storage

  if (tid < 128) {
    tl[tid] = t[tid];
    cpS[tid] = coef[tid];
    imS[tid] = coef[128 + tid];
    ihS[tid] = coef[256 + tid];
    hS[tid]  = coef[384 + tid];
  }
  __syncthreads();
  float xp = (p < T_) ? tl[p] : 0.5f * (tl[p - T_] + tl[p - T_ + 1]);
  if (tid < 32) {
    int n = tid;
    float u = (float)n * (1.0f / 31.0f);
    float q = xp * u;
    float qc = fminf(fmaxf(q, tl[0]), tl[127]);
    int i = (int)floorf(qc * 127.0f);
    i = max(0, min(126, i));
    while (i > 0 && qc < tl[i]) --i;
    while (i < 126 && qc >= tl[i + 1]) ++i;
    float h = tl[i + 1] - tl[i];
    float a = (tl[i + 1] - qc) / h, b = (qc - tl[i]) / h;
    sn[n] = q; idn[n] = i; an[n] = a; bn[n] = b;
    float h26 = h * h * (1.0f / 6.0f);
    cA[n] = (a * a * a - a) * h26;
    cB[n] = (b * b * b - b) * h26;
  }
  __syncthreads();
  // phase A: threads 0-127 Thomas solve (M -> bf16 LDS); 128-511 hden
  if (tid < 128) {
    int d = tid;
    float ym = yg[d], yc = yg[128 + d];
    float dprev = 0.0f;
    #pragma unroll 4
    for (int i = 1; i <= 126; ++i) {
      float yp = yg[(i + 1) * 128 + d];
      float rhs = 6.0f * ((yp - yc) * ihS[i] - (yc - ym) * ihS[i - 1]);
      dprev = (rhs - hS[i - 1] * dprev) * imS[i];
      mh[i * 128 + d] = f2b(dprev);     // dp[i]
      ym = yc; yc = yp;
    }
    float x = dprev;                     // fp32 dp[126] = M[126]
    #pragma unroll 4
    for (int i = 125; i >= 1; --i) {
      x = b2f(mh[i * 128 + d]) - cpS[i] * x;
      mh[i * 128 + d] = f2b(x);
    }
    mh[d] = 0;
    mh[127 * 128 + d] = 0;
  } else {
    int base = tid - 128;
    #pragma unroll
    for (int k = 0; k < 6; ++k) {
      int idx = base + k * 384;
      if (idx < 2048) {
        int n = idx >> 6, c = idx & 63;
        hdl[idx] = tanh_fast(fmaf(xp, Wk1[c], fmaf(sn[n], Wk1[64 + c], bk1[c])));
      }
    }
  }
  __syncthreads();
  // phase 1: ysT[d][n] (M from bf16 LDS, yg from L2)
  {
    int d = tid & 127, q = tid >> 7;
    #pragma unroll
    for (int pass = 0; pass < 8; ++pass) {
      int n = pass * 4 + q;
      int i = idn[n];
      float m0 = b2f(mh[i * 128 + d]), m1 = b2f(mh[(i + 1) * 128 + d]);
      bufA[d * 36 + n] = an[n] * yg[i * 128 + d] + bn[n] * yg[(i + 1) * 128 + d]
                       + cA[n] * m0 + cB[n] * m1;
    }
  }
  __syncthreads();
  // phase 2: h1T[n][hc] = tanh(ys @ W1 + b1) into R1f (M dead)
  {
    int hcb = (tid & 127) * 2;
    int nb = (tid >> 7) * 8;
    float acc[2][8];
    float2 b12 = *(const float2*)&b1[hcb];
    #pragma unroll
    for (int k = 0; k < 8; ++k) { acc[0][k] = b12.x; acc[1][k] = b12.y; }
    #pragma unroll 4
    for (int d = 0; d < 128; ++d) {
      float2 w2 = *(const float2*)&W1[d * 256 + hcb];
      float4 ya = *(const float4*)&bufA[d * 36 + nb];
      float4 yb = *(const float4*)&bufA[d * 36 + nb + 4];
      float y_[8] = {ya.x, ya.y, ya.z, ya.w, yb.x, yb.y, yb.z, yb.w};
      #pragma unroll
      for (int k = 0; k < 8; ++k) {
        acc[0][k] = fmaf(w2.x, y_[k], acc[0][k]);
        acc[1][k] = fmaf(w2.y, y_[k], acc[1][k]);
      }
    }
    #pragma unroll
    for (int k = 0; k < 8; ++k) {
      float2 v = make_float2(tanh_fast(acc[0][k]), tanh_fast(acc[1][k]));
      *(float2*)&R1f[(nb + k) * 256 + hcb] = v;
    }
  }
  __syncthreads();
  // phase 3: fy[n][j] = wq_n*(h1 @ W2 + b2); W2 staged through LDS (R2),
  // 8 chunks of 32 c. ysT in R2 is dead now.
  {
    int jb = (tid & 31) * 4;
    int ng = tid >> 5;            // 16 groups x 2 rows
    int n0 = ng * 2, n1 = n0 + 1;
    float acc[2][4];
    float4 b24 = *(const float4*)&b2[jb];
    acc[0][0] = b24.x; acc[0][1] = b24.y; acc[0][2] = b24.z; acc[0][3] = b24.w;
    acc[1][0] = b24.x; acc[1][1] = b24.y; acc[1][2] = b24.z; acc[1][3] = b24.w;
    float* stage = bufA;          // 4096 floats
    for (int cc = 0; cc < 8; ++cc) {
      {  // coop load W2 chunk: 32 c x 128 j = 16KB, coalesced
        const float4* src = (const float4*)(W2 + cc * 4096);
        float4* dst = (float4*)stage;
        dst[tid * 2] = src[tid * 2];
        dst[tid * 2 + 1] = src[tid * 2 + 1];
      }
      __syncthreads();
      #pragma unroll 8
      for (int cl = 0; cl < 32; ++cl) {
        int c = cc * 32 + cl;
        float4 w4 = *(const float4*)&stage[cl * 128 + jb];
        float h0 = R1f[n0 * 256 + c];
        float h1 = R1f[n1 * 256 + c];
        acc[0][0] = fmaf(h0, w4.x, acc[0][0]); acc[0][1] = fmaf(h0, w4.y, acc[0][1]);
        acc[0][2] = fmaf(h0, w4.z, acc[0][2]); acc[0][3] = fmaf(h0, w4.w, acc[0][3]);
        acc[1][0] = fmaf(h1, w4.x, acc[1][0]); acc[1][1] = fmaf(h1, w4.y, acc[1][1]);
        acc[1][2] = fmaf(h1, w4.z, acc[1][2]); acc[1][3] = fmaf(h1, w4.w, acc[1][3]);
      }
      __syncthreads();
    }
    // h1T fully consumed; write wq-folded fy into R1f[n][128]
    float wq0 = (n0 == 0) ? 0.5f : 1.0f;
    float wq1 = (n1 == 31) ? 0.5f : 1.0f;
    *(float4*)&R1f[n0 * 128 + jb] =
        make_float4(acc[0][0] * wq0, acc[0][1] * wq0, acc[0][2] * wq0, acc[0][3] * wq0);
    *(float4*)&R1f[n1 * 128 + jb] =
        make_float4(acc[1][0] * wq1, acc[1][1] * wq1, acc[1][2] * wq1, acc[1][3] * wq1);
  }
  __syncthreads();
  // phase 4: S[c][j] = sum_n hden[n][c] * fyw[n][j]; fybar row = sum_n fyw
  {
    int jb = (tid & 31) * 4;
    int cg = tid >> 5;            // 16 groups x 4 c
    float acc[4][4];
    #pragma unroll
    for (int c = 0; c < 4; ++c)
      #pragma unroll
      for (int jj = 0; jj < 4; ++jj) acc[c][jj] = 0.0f;
    float fyb[4] = {0.f, 0.f, 0.f, 0.f};
    #pragma unroll 4
    for (int n = 0; n < 32; ++n) {
      float4 f4 = *(const float4*)&R1f[n * 128 + jb];
      float f_[4] = {f4.x, f4.y, f4.z, f4.w};
      if (cg == 0) {
        fyb[0] += f_[0]; fyb[1] += f_[1]; fyb[2] += f_[2]; fyb[3] += f_[3];
      }
      float4 h4 = *(const float4*)&hdl[n * 64 + cg * 4];
      float h_[4] = {h4.x, h4.y, h4.z, h4.w};
      #pragma unroll
      for (int c = 0; c < 4; ++c)
        #pragma unroll
        for (int jj = 0; jj < 4; ++jj)
          acc[c][jj] = fmaf(h_[c], f_[jj], acc[c][jj]);
    }
    float* sp = S + p * SROW;
    #pragma unroll
    for (int c = 0; c < 4; ++c)
      *(float4*)&sp[(cg * 4 + c) * 128 + jb] =
          make_float4(acc[c][0], acc[c][1], acc[c][2], acc[c][3]);
    if (cg == 0)
      *(float4*)&sp[8192 + jb] = make_float4(fyb[0], fyb[1], fyb[2], fyb[3]);
  }
}

// partial[cc][p][i] = sum over k in c-chunk cc of S[p][k]*WT[k][i]
__global__ __launch_bounds__(256) void k_gemm(const float* __restrict__ S,
                                              const float* __restrict__ WT,
                                              float* __restrict__ part) {
  int pt = blockIdx.x;   // 0..16  (15 p each)
  int cc = blockIdx.y;   // 0..32  (2 c each, last has 1)
  int c0 = cc * 2;
  int nk = (c0 + 1 < 65) ? 256 : 128;
  int p0 = pt * 15;
  int tid = threadIdx.x;
  __shared__ float Sl[15 * 256];
  for (int idx = tid; idx < 15 * 256; idx += 256) {
    int pl = idx >> 8, kk = idx & 255;
    Sl[idx] = (kk < nk) ? S[(p0 + pl) * SROW + c0 * 128 + kk] : 0.0f;
  }
  __syncthreads();
  int i4 = (tid & 31) * 4;
  int grp = tid >> 5;                       // rows p0+grp and p0+grp+8
  int grp2 = (grp < 7) ? grp + 8 : grp;
  const float* wb = WT + c0 * 16384 + i4;
  float a0[4] = {0.f, 0.f, 0.f, 0.f};
  float a1[4] = {0.f, 0.f, 0.f, 0.f};
  #pragma unroll 8
  for (int kk = 0; kk < nk; ++kk) {
    float4 w = *(const float4*)&wb[kk * 128];
    float s0 = Sl[grp * 256 + kk];
    float s1 = Sl[grp2 * 256 + kk];
    a0[0] = fmaf(w.x, s0, a0[0]); a0[1] = fmaf(w.y, s0, a0[1]);
    a0[2] = fmaf(w.z, s0, a0[2]); a0[3] = fmaf(w.w, s0, a0[3]);
    a1[0] = fmaf(w.x, s1, a1[0]); a1[1] = fmaf(w.y, s1, a1[1]);
    a1[2] = fmaf(w.z, s1, a1[2]); a1[3] = fmaf(w.w, s1, a1[3]);
  }
  *(float4*)&part[cc * GSZ + (p0 + grp) * 128 + i4] =
      make_float4(a0[0], a0[1], a0[2], a0[3]);
  if (grp < 7)
    *(float4*)&part[cc * GSZ + (p0 + grp + 8) * 128 + i4] =
        make_float4(a1[0], a1[1], a1[2], a1[3]);
}

__global__ __launch_bounds__(256) void k_reduce(const float* __restrict__ part,
                                                const float* __restrict__ t,
                                                float* __restrict__ g) {
  int idx = blockIdx.x * 256 + threadIdx.x;
  if (idx >= GSZ) return;
  float s = 0.f;
  #pragma unroll
  for (int cc = 0; cc < NCH; ++cc) s += part[cc * GSZ + idx];
  int p = idx >> 7;
  float xp = (p < T_) ? t[p] : 0.5f * (t[p - T_] + t[p - T_ + 1]);
  g[idx] = s * (xp * (1.0f / 31.0f));
}

// Simpson increments (parallel, LDS) + cumulative sum -> new yg (+ d_out)
__global__ __launch_bounds__(256) void k_final(const float* __restrict__ t,
                                               const float* __restrict__ z0,
                                               const float* __restrict__ g,
                                               float* __restrict__ yg,
                                               float* __restrict__ out, int wout) {
  __shared__ float inc[127 * 128];   // 65024 B
  int tid = threadIdx.x;
  for (int idx = tid; idx < 127 * 128; idx += 256) {
    int k = idx >> 7, d = idx & 127;
    float h = t[k + 1] - t[k];
    inc[idx] = h * (1.0f / 6.0f) *
        (g[k * 128 + d] + 4.0f * g[(T_ + k) * 128 + d] + g[(k + 1) * 128 + d]);
  }
  __syncthreads();
  if (tid < 128) {
    int d = tid;
    float acc = z0[d];
    yg[d] = acc;
    if (wout) out[d] = acc;
    #pragma unroll 4
    for (int k = 0; k < 127; ++k) {
      acc += inc[k * 128 + d];
      yg[(k + 1) * 128 + d] = acc;
      if (wout) out[(k + 1) * 128 + d] = acc;
    }
  }
}

extern "C" void kernel_launch(void* const* d_in, const int* in_sizes, int n_in,
                              void* d_out, int out_size, void* d_ws, size_t ws_size,
                              hipStream_t stream) {
  const float* z0  = (const float*)d_in[0];
  const float* t   = (const float*)d_in[1];
  const float* W1  = (const float*)d_in[2];
  const float* b1  = (const float*)d_in[3];
  const float* W2  = (const float*)d_in[4];
  const float* b2  = (const float*)d_in[5];
  const float* Wk1 = (const float*)d_in[6];
  const float* bk1 = (const float*)d_in[7];
  const float* Wk2 = (const float*)d_in[8];
  const float* bk2 = (const float*)d_in[9];
  float* out = (float*)d_out;
  float* ws  = (float*)d_ws;

  float* yg   = ws + OFF_YG;
  float* WT   = ws + OFF_WT;
  float* S    = ws + OFF_S;
  float* part = ws + OFF_PART;
  float* g    = ws + OFF_G;
  float* coef = ws + OFF_COEF;

  k_init<<<dim3(64), dim3(256), 0, stream>>>(z0, yg);
  k_precoef<<<dim3(1), dim3(128), 0, stream>>>(t, coef);
  k_transpose<<<dim3(65), dim3(256), 0, stream>>>(Wk2, bk2, WT);
  for (int it = 0; it < 3; ++it) {
    k_point<<<dim3(255), dim3(512), 0, stream>>>(t, coef, yg, W1, b1, W2, b2,
                                                 Wk1, bk1, S);
    k_gemm<<<dim3(17, NCH), dim3(256), 0, stream>>>(S, WT, part);
    k_reduce<<<dim3(128), dim3(256), 0, stream>>>(part, t, g);
    k_final<<<dim3(1), dim3(256), 0, stream>>>(t, z0, g, yg, out, (it == 2) ? 1 : 0);
  }
}

// Round 5
// 310.287 us; speedup vs baseline: 3.9730x; 1.0337x over previous
//
#include <hip/hip_runtime.h>
#include <hip/hip_fp16.h>

// Problem constants
#define D_  128
#define T_  128
#define P_  255           // 2T-1 evaluation points
#define SROW 8320         // 65*128 (64 hden rows + 1 fybar row)
#define NCH  33
#define GSZ  32640        // 255*128

// workspace offsets (float slots)
#define OFF_YG    0          // float yg[128*128]
#define OFF_COEF  16384      // float: [256..383] = invh[127]
#define OFF_AINV  16896      // float Ainv[128*128]
#define OFF_G     33280      // float G[128*128]
#define OFF_E     49664      // half E[8160*128]      (522240 slots)
#define OFF_HDW   571904     // half HDW[255*2080]    (265200 slots)
#define OFF_WT    837104     // float WT[65*16384]
#define OFF_B     1902064    // half ys[8160*128] THEN half S[255*8320] (1060800 slots)
#define OFF_A     2962864    // half h1[8160*256] THEN float part[33*32640] (1077120)
#define OFF_G2    4039984    // float g[32640]
// end = 4072624 floats = 16.3 MiB (< 16.5 MiB proven available)

__device__ __forceinline__ float tanh_fast(float x) {
  float e = __expf(2.0f * x);
  return 1.0f - 2.0f / (e + 1.0f);
}

__global__ __launch_bounds__(256) void k_init(const float* __restrict__ z0,
                                              float* __restrict__ yg) {
  int idx = blockIdx.x * 256 + threadIdx.x;
  if (idx < T_ * D_) yg[idx] = z0[idx & (D_ - 1)];
}

// Tridiagonal inverse: thread d solves A x = e_d (Thomas). Also writes invh.
__global__ __launch_bounds__(128) void k_inv(const float* __restrict__ t,
                                             float* __restrict__ coef,
                                             float* __restrict__ Ainv) {
  __shared__ float tl[128];
  __shared__ float cpL[128], imL[128];
  __shared__ float dpL[127 * 128];
  int d = threadIdx.x;
  tl[d] = t[d];
  __syncthreads();
  if (d == 0) {
    cpL[0] = 0.0f;
    float cprev = 0.0f;
    for (int i = 1; i <= 126; ++i) {
      float hm = tl[i] - tl[i - 1], hi = tl[i + 1] - tl[i];
      float m = 2.0f * (hm + hi) - hm * cprev;
      float im = 1.0f / m;
      imL[i] = im;
      cprev = hi * im;
      cpL[i] = cprev;
    }
  }
  if (d < 127) coef[256 + d] = 1.0f / (tl[d + 1] - tl[d]);   // invh
  __syncthreads();
  float dprev = (d == 0) ? 1.0f : 0.0f;
  dpL[d] = dprev;
  for (int i = 1; i <= 126; ++i) {
    float rhs = (i == d) ? 1.0f : 0.0f;
    float hm = tl[i] - tl[i - 1];
    dprev = (rhs - hm * dprev) * imL[i];
    dpL[i * 128 + d] = dprev;
  }
  float x = (d == 127) ? 1.0f : 0.0f;   // row 127 of A is identity
  Ainv[127 * 128 + d] = x;
  for (int i = 126; i >= 0; --i) {
    x = dpL[i * 128 + d] - cpL[i] * x;
    Ainv[i * 128 + d] = x;
  }
}

// G = Ainv @ R (R = tridiagonal rhs operator; rows 0,127 zero)
__global__ __launch_bounds__(256) void k_G(const float* __restrict__ coef,
                                           const float* __restrict__ Ainv,
                                           float* __restrict__ G) {
  int idx = blockIdx.x * 256 + threadIdx.x;   // 64 blocks -> 16384
  int a = idx >> 7, b = idx & 127;
  const float* ih = coef + 256;
  float acc = 0.0f;
  if (b >= 2)             acc += Ainv[a * 128 + b - 1] * (6.0f * ih[b - 1]);
  if (b >= 1 && b <= 126) acc += Ainv[a * 128 + b] * (-6.0f * (ih[b - 1] + ih[b]));
  if (b <= 125)           acc += Ainv[a * 128 + b + 1] * (6.0f * ih[b]);
  G[idx] = acc;
}

// E rows (spline-eval operator) + wq-folded hden table. Iteration-invariant.
__global__ __launch_bounds__(256) void k_EH(const float* __restrict__ t,
                                            const float* __restrict__ Wk1,
                                            const float* __restrict__ bk1,
                                            const float* __restrict__ G,
                                            __half* __restrict__ E,
                                            __half* __restrict__ HDW) {
  __shared__ float tl[128];
  __shared__ float sn[32], an[32], bn[32], cA[32], cB[32];
  __shared__ int idn[32];
  int p = blockIdx.x, tid = threadIdx.x;
  if (tid < 128) tl[tid] = t[tid];
  __syncthreads();
  float xp = (p < T_) ? tl[p] : 0.5f * (tl[p - T_] + tl[p - T_ + 1]);
  if (tid < 32) {
    int n = tid;
    float u = (float)n * (1.0f / 31.0f);
    float q = xp * u;
    float qc = fminf(fmaxf(q, tl[0]), tl[127]);
    int i = (int)floorf(qc * 127.0f);
    i = max(0, min(126, i));
    while (i > 0 && qc < tl[i]) --i;
    while (i < 126 && qc >= tl[i + 1]) ++i;
    float h = tl[i + 1] - tl[i];
    float a = (tl[i + 1] - qc) / h, b = (qc - tl[i]) / h;
    sn[n] = q; idn[n] = i; an[n] = a; bn[n] = b;
    float h26 = h * h * (1.0f / 6.0f);
    cA[n] = (a * a * a - a) * h26;
    cB[n] = (b * b * b - b) * h26;
  }
  __syncthreads();
  #pragma unroll
  for (int pass = 0; pass < 16; ++pass) {
    int n = pass * 2 + (tid >> 7);
    int b = tid & 127;
    int i = idn[n];
    float v = cA[n] * G[i * 128 + b] + cB[n] * G[(i + 1) * 128 + b];
    if (b == i) v += an[n];
    if (b == i + 1) v += bn[n];
    E[(p * 32 + n) * 128 + b] = __float2half(v);
  }
  #pragma unroll
  for (int k = 0; k < 9; ++k) {
    int idx = k * 256 + tid;
    if (idx < 2080) {
      int c = idx >> 5, n = idx & 31;
      float wq = (n == 0 || n == 31) ? 0.5f : 1.0f;
      float v = (c < 64)
          ? wq * tanh_fast(fmaf(xp, Wk1[c], fmaf(sn[n], Wk1[64 + c], bk1[c])))
          : wq;
      HDW[p * 2080 + idx] = __float2half(v);   // layout [c][n]
    }
  }
}

// WT[c][j][i] = Wrow_c[i*128+j]
__global__ __launch_bounds__(256) void k_transpose(const float* __restrict__ Wk2,
                                                   const float* __restrict__ bk2,
                                                   float* __restrict__ WT) {
  int c = blockIdx.x;
  const float* src = (c < 64) ? (Wk2 + c * 16384) : bk2;
  __shared__ float tile[16384];
  #pragma unroll 8
  for (int k = 0; k < 64; ++k) {
    int idx = k * 256 + threadIdx.x;
    int i = idx >> 7, j = idx & 127;
    tile[j * 128 + (i ^ (j & 31))] = src[idx];
  }
  __syncthreads();
  float* dst = WT + c * 16384;
  #pragma unroll 8
  for (int k = 0; k < 64; ++k) {
    int idx = k * 256 + threadIdx.x;
    int jj = idx >> 7, ii = idx & 127;
    dst[idx] = tile[jj * 128 + (ii ^ (jj & 31))];
  }
}

// ys = E @ yg : block (p, dh) computes 32n x 64d, K=128
__global__ __launch_bounds__(256) void k_ys(const float* __restrict__ yg,
                                            const __half* __restrict__ E,
                                            __half* __restrict__ ysh) {
  __shared__ float Bc[64 * 64];
  __shared__ __half Al[32 * 128];
  int p = blockIdx.x, dh = blockIdx.y, tid = threadIdx.x;
  {
    const __half* src = E + p * 4096;
    #pragma unroll
    for (int k = 0; k < 16; ++k) Al[k * 256 + tid] = src[k * 256 + tid];
  }
  int jb = (tid & 15) * 4;
  int nA = tid >> 4;
  float a0[4] = {0.f, 0.f, 0.f, 0.f}, a1[4] = {0.f, 0.f, 0.f, 0.f};
  for (int ch = 0; ch < 2; ++ch) {
    __syncthreads();
    #pragma unroll
    for (int k = 0; k < 16; ++k) {
      int idx = k * 256 + tid;
      Bc[idx] = yg[(ch * 64 + (idx >> 6)) * 128 + dh * 64 + (idx & 63)];
    }
    __syncthreads();
    #pragma unroll 4
    for (int bl = 0; bl < 64; ++bl) {
      int b = ch * 64 + bl;
      float e0 = __half2float(Al[nA * 128 + b]);
      float e1 = __half2float(Al[(nA + 16) * 128 + b]);
      float4 w = *(const float4*)&Bc[bl * 64 + jb];
      a0[0] = fmaf(e0, w.x, a0[0]); a0[1] = fmaf(e0, w.y, a0[1]);
      a0[2] = fmaf(e0, w.z, a0[2]); a0[3] = fmaf(e0, w.w, a0[3]);
      a1[0] = fmaf(e1, w.x, a1[0]); a1[1] = fmaf(e1, w.y, a1[1]);
      a1[2] = fmaf(e1, w.z, a1[2]); a1[3] = fmaf(e1, w.w, a1[3]);
    }
  }
  int r0 = (p * 32 + nA) * 128 + dh * 64 + jb;
  int r1 = r0 + 16 * 128;
  *(__half2*)&ysh[r0]     = __floats2half2_rn(a0[0], a0[1]);
  *(__half2*)&ysh[r0 + 2] = __floats2half2_rn(a0[2], a0[3]);
  *(__half2*)&ysh[r1]     = __floats2half2_rn(a1[0], a1[1]);
  *(__half2*)&ysh[r1 + 2] = __floats2half2_rn(a1[2], a1[3]);
}

// h1 = tanh(ys @ W1 + b1) : block (p, hq) -> 32n x 64hc, K=128
__global__ __launch_bounds__(256) void k_mlp1(const __half* __restrict__ ysh,
                                              const float* __restrict__ W1,
                                              const float* __restrict__ b1,
                                              __half* __restrict__ h1h) {
  __shared__ float Bc[64 * 64];
  __shared__ __half Al[32 * 128];
  int p = blockIdx.x, hq = blockIdx.y, tid = threadIdx.x;
  {
    const __half* src = ysh + p * 4096;
    #pragma unroll
    for (int k = 0; k < 16; ++k) Al[k * 256 + tid] = src[k * 256 + tid];
  }
  int jb = (tid & 15) * 4;
  int nA = tid >> 4;
  float a0[4] = {0.f, 0.f, 0.f, 0.f}, a1[4] = {0.f, 0.f, 0.f, 0.f};
  for (int ch = 0; ch < 2; ++ch) {
    __syncthreads();
    #pragma unroll
    for (int k = 0; k < 16; ++k) {
      int idx = k * 256 + tid;
      Bc[idx] = W1[(ch * 64 + (idx >> 6)) * 256 + hq * 64 + (idx & 63)];
    }
    __syncthreads();
    #pragma unroll 4
    for (int bl = 0; bl < 64; ++bl) {
      int b = ch * 64 + bl;
      float e0 = __half2float(Al[nA * 128 + b]);
      float e1 = __half2float(Al[(nA + 16) * 128 + b]);
      float4 w = *(const float4*)&Bc[bl * 64 + jb];
      a0[0] = fmaf(e0, w.x, a0[0]); a0[1] = fmaf(e0, w.y, a0[1]);
      a0[2] = fmaf(e0, w.z, a0[2]); a0[3] = fmaf(e0, w.w, a0[3]);
      a1[0] = fmaf(e1, w.x, a1[0]); a1[1] = fmaf(e1, w.y, a1[1]);
      a1[2] = fmaf(e1, w.z, a1[2]); a1[3] = fmaf(e1, w.w, a1[3]);
    }
  }
  float4 bb = *(const float4*)&b1[hq * 64 + jb];
  int r0 = (p * 32 + nA) * 256 + hq * 64 + jb;
  int r1 = r0 + 16 * 256;
  *(__half2*)&h1h[r0] =
      __floats2half2_rn(tanh_fast(a0[0] + bb.x), tanh_fast(a0[1] + bb.y));
  *(__half2*)&h1h[r0 + 2] =
      __floats2half2_rn(tanh_fast(a0[2] + bb.z), tanh_fast(a0[3] + bb.w));
  *(__half2*)&h1h[r1] =
      __floats2half2_rn(tanh_fast(a1[0] + bb.x), tanh_fast(a1[1] + bb.y));
  *(__half2*)&h1h[r1 + 2] =
      __floats2half2_rn(tanh_fast(a1[2] + bb.z), tanh_fast(a1[3] + bb.w));
}

// fy = h1 @ W2 + b2 fused with S accumulation: block (p, jh) -> 32n x 64j, K=256
__global__ __launch_bounds__(256) void k_mlp2S(const __half* __restrict__ h1h,
                                               const float* __restrict__ W2,
                                               const float* __restrict__ b2,
                                               const __half* __restrict__ HDW,
                                               __half* __restrict__ Sh) {
  __shared__ float Bc[64 * 64];      // 16KB
  __shared__ __half Al[32 * 256];    // 16KB
  __shared__ float fyL[32 * 64];     // 8KB
  __shared__ __half hdwL[32 * 66];   // [n][c], padded
  int p = blockIdx.x, jh = blockIdx.y, tid = threadIdx.x;
  {
    const __half* src = h1h + p * 8192;
    #pragma unroll
    for (int k = 0; k < 32; ++k) Al[k * 256 + tid] = src[k * 256 + tid];
  }
  {
    const __half* src = HDW + p * 2080;
    #pragma unroll
    for (int k = 0; k < 9; ++k) {
      int idx = k * 256 + tid;
      if (idx < 2080) hdwL[(idx & 31) * 66 + (idx >> 5)] = src[idx];
    }
  }
  int jb = (tid & 15) * 4;
  int nA = tid >> 4;
  float a0[4] = {0.f, 0.f, 0.f, 0.f}, a1[4] = {0.f, 0.f, 0.f, 0.f};
  for (int ch = 0; ch < 4; ++ch) {
    __syncthreads();
    #pragma unroll
    for (int k = 0; k < 16; ++k) {
      int idx = k * 256 + tid;
      Bc[idx] = W2[(ch * 64 + (idx >> 6)) * 128 + jh * 64 + (idx & 63)];
    }
    __syncthreads();
    #pragma unroll 4
    for (int bl = 0; bl < 64; ++bl) {
      int b = ch * 64 + bl;
      float e0 = __half2float(Al[nA * 256 + b]);
      float e1 = __half2float(Al[(nA + 16) * 256 + b]);
      float4 w = *(const float4*)&Bc[bl * 64 + jb];
      a0[0] = fmaf(e0, w.x, a0[0]); a0[1] = fmaf(e0, w.y, a0[1]);
      a0[2] = fmaf(e0, w.z, a0[2]); a0[3] = fmaf(e0, w.w, a0[3]);
      a1[0] = fmaf(e1, w.x, a1[0]); a1[1] = fmaf(e1, w.y, a1[1]);
      a1[2] = fmaf(e1, w.z, a1[2]); a1[3] = fmaf(e1, w.w, a1[3]);
    }
  }
  float4 bb = *(const float4*)&b2[jh * 64 + jb];
  fyL[nA * 64 + jb + 0] = a0[0] + bb.x;
  fyL[nA * 64 + jb + 1] = a0[1] + bb.y;
  fyL[nA * 64 + jb + 2] = a0[2] + bb.z;
  fyL[nA * 64 + jb + 3] = a0[3] + bb.w;
  fyL[(nA + 16) * 64 + jb + 0] = a1[0] + bb.x;
  fyL[(nA + 16) * 64 + jb + 1] = a1[1] + bb.y;
  fyL[(nA + 16) * 64 + jb + 2] = a1[2] + bb.z;
  fyL[(nA + 16) * 64 + jb + 3] = a1[3] + bb.w;
  __syncthreads();
  // S[c][j] = sum_n hdw[c][n]*fy[n][j] for c in cg*4..+4
  int cg = tid >> 4;
  float acc[4][4];
  #pragma unroll
  for (int c = 0; c < 4; ++c)
    #pragma unroll
    for (int j = 0; j < 4; ++j) acc[c][j] = 0.0f;
  #pragma unroll 4
  for (int n = 0; n < 32; ++n) {
    float4 f = *(const float4*)&fyL[n * 64 + jb];
    float f_[4] = {f.x, f.y, f.z, f.w};
    float h_[4];
    #pragma unroll
    for (int c = 0; c < 4; ++c) h_[c] = __half2float(hdwL[n * 66 + cg * 4 + c]);
    #pragma unroll
    for (int c = 0; c < 4; ++c)
      #pragma unroll
      for (int j = 0; j < 4; ++j) acc[c][j] = fmaf(h_[c], f_[j], acc[c][j]);
  }
  __half* sp = Sh + p * SROW + jh * 64;
  #pragma unroll
  for (int c = 0; c < 4; ++c) {
    int row = cg * 4 + c;
    *(__half2*)&sp[row * 128 + jb]     = __floats2half2_rn(acc[c][0], acc[c][1]);
    *(__half2*)&sp[row * 128 + jb + 2] = __floats2half2_rn(acc[c][2], acc[c][3]);
  }
  if (tid < 16) {   // fybar row c=64
    int j4 = tid * 4;
    float a4[4] = {0.f, 0.f, 0.f, 0.f};
    for (int n = 0; n < 32; ++n) {
      float4 f = *(const float4*)&fyL[n * 64 + j4];
      float w = __half2float(hdwL[n * 66 + 64]);
      a4[0] = fmaf(w, f.x, a4[0]); a4[1] = fmaf(w, f.y, a4[1]);
      a4[2] = fmaf(w, f.z, a4[2]); a4[3] = fmaf(w, f.w, a4[3]);
    }
    *(__half2*)&sp[64 * 128 + j4]     = __floats2half2_rn(a4[0], a4[1]);
    *(__half2*)&sp[64 * 128 + j4 + 2] = __floats2half2_rn(a4[2], a4[3]);
  }
}

// partial[cc][p][i] = sum over k in c-chunk cc of S[p][k]*WT[k][i]
__global__ __launch_bounds__(256) void k_gemm(const __half* __restrict__ Sh,
                                              const float* __restrict__ WT,
                                              float* __restrict__ part) {
  int pt = blockIdx.x;   // 0..16
  int cc = blockIdx.y;   // 0..32
  int c0 = cc * 2;
  int nk = (c0 + 1 < 65) ? 256 : 128;
  int p0 = pt * 15;
  int tid = threadIdx.x;
  __shared__ float Sl[15 * 256];
  for (int idx = tid; idx < 15 * 256; idx += 256) {
    int pl = idx >> 8, kk = idx & 255;
    Sl[idx] = (kk < nk) ? __half2float(Sh[(p0 + pl) * SROW + c0 * 128 + kk]) : 0.0f;
  }
  __syncthreads();
  int i4 = (tid & 31) * 4;
  int grp = tid >> 5;
  int grp2 = (grp < 7) ? grp + 8 : grp;
  const float* wb = WT + c0 * 16384 + i4;
  float a0[4] = {0.f, 0.f, 0.f, 0.f};
  float a1[4] = {0.f, 0.f, 0.f, 0.f};
  #pragma unroll 8
  for (int kk = 0; kk < nk; ++kk) {
    float4 w = *(const float4*)&wb[kk * 128];
    float s0 = Sl[grp * 256 + kk];
    float s1 = Sl[grp2 * 256 + kk];
    a0[0] = fmaf(w.x, s0, a0[0]); a0[1] = fmaf(w.y, s0, a0[1]);
    a0[2] = fmaf(w.z, s0, a0[2]); a0[3] = fmaf(w.w, s0, a0[3]);
    a1[0] = fmaf(w.x, s1, a1[0]); a1[1] = fmaf(w.y, s1, a1[1]);
    a1[2] = fmaf(w.z, s1, a1[2]); a1[3] = fmaf(w.w, s1, a1[3]);
  }
  *(float4*)&part[cc * GSZ + (p0 + grp) * 128 + i4] =
      make_float4(a0[0], a0[1], a0[2], a0[3]);
  if (grp < 7)
    *(float4*)&part[cc * GSZ + (p0 + grp + 8) * 128 + i4] =
        make_float4(a1[0], a1[1], a1[2], a1[3]);
}

__global__ __launch_bounds__(256) void k_reduce(const float* __restrict__ part,
                                                const float* __restrict__ t,
                                                float* __restrict__ g) {
  int idx = blockIdx.x * 256 + threadIdx.x;
  if (idx >= GSZ) return;
  float s = 0.f;
  #pragma unroll
  for (int cc = 0; cc < NCH; ++cc) s += part[cc * GSZ + idx];
  int p = idx >> 7;
  float xp = (p < T_) ? t[p] : 0.5f * (t[p - T_] + t[p - T_ + 1]);
  g[idx] = s * (xp * (1.0f / 31.0f));
}

__global__ __launch_bounds__(256) void k_final(const float* __restrict__ t,
                                               const float* __restrict__ z0,
                                               const float* __restrict__ g,
                                               float* __restrict__ yg,
                                               float* __restrict__ out, int wout) {
  __shared__ float inc[127 * 128];
  int tid = threadIdx.x;
  for (int idx = tid; idx < 127 * 128; idx += 256) {
    int k = idx >> 7, d = idx & 127;
    float h = t[k + 1] - t[k];
    inc[idx] = h * (1.0f / 6.0f) *
        (g[k * 128 + d] + 4.0f * g[(T_ + k) * 128 + d] + g[(k + 1) * 128 + d]);
  }
  __syncthreads();
  if (tid < 128) {
    int d = tid;
    float acc = z0[d];
    yg[d] = acc;
    if (wout) out[d] = acc;
    #pragma unroll 4
    for (int k = 0; k < 127; ++k) {
      acc += inc[k * 128 + d];
      yg[(k + 1) * 128 + d] = acc;
      if (wout) out[(k + 1) * 128 + d] = acc;
    }
  }
}

extern "C" void kernel_launch(void* const* d_in, const int* in_sizes, int n_in,
                              void* d_out, int out_size, void* d_ws, size_t ws_size,
                              hipStream_t stream) {
  const float* z0  = (const float*)d_in[0];
  const float* t   = (const float*)d_in[1];
  const float* W1  = (const float*)d_in[2];
  const float* b1  = (const float*)d_in[3];
  const float* W2  = (const float*)d_in[4];
  const float* b2  = (const float*)d_in[5];
  const float* Wk1 = (const float*)d_in[6];
  const float* bk1 = (const float*)d_in[7];
  const float* Wk2 = (const float*)d_in[8];
  const float* bk2 = (const float*)d_in[9];
  float* out = (float*)d_out;
  float* ws  = (float*)d_ws;

  float*  yg   = ws + OFF_YG;
  float*  coef = ws + OFF_COEF;
  float*  Ainv = ws + OFF_AINV;
  float*  G    = ws + OFF_G;
  __half* E    = (__half*)(ws + OFF_E);
  __half* HDW  = (__half*)(ws + OFF_HDW);
  float*  WT   = ws + OFF_WT;
  __half* ysh  = (__half*)(ws + OFF_B);   // overlaid with Sh (disjoint lifetime)
  __half* Sh   = (__half*)(ws + OFF_B);
  __half* h1h  = (__half*)(ws + OFF_A);   // overlaid with part
  float*  part = ws + OFF_A;
  float*  g    = ws + OFF_G2;

  k_init<<<dim3(64), dim3(256), 0, stream>>>(z0, yg);
  k_inv<<<dim3(1), dim3(128), 0, stream>>>(t, coef, Ainv);
  k_transpose<<<dim3(65), dim3(256), 0, stream>>>(Wk2, bk2, WT);
  k_G<<<dim3(64), dim3(256), 0, stream>>>(coef, Ainv, G);
  k_EH<<<dim3(255), dim3(256), 0, stream>>>(t, Wk1, bk1, G, E, HDW);
  for (int it = 0; it < 3; ++it) {
    k_ys<<<dim3(255, 2), dim3(256), 0, stream>>>(yg, E, ysh);
    k_mlp1<<<dim3(255, 4), dim3(256), 0, stream>>>(ysh, W1, b1, h1h);
    k_mlp2S<<<dim3(255, 2), dim3(256), 0, stream>>>(h1h, W2, b2, HDW, Sh);
    k_gemm<<<dim3(17, NCH), dim3(256), 0, stream>>>(Sh, WT, part);
    k_reduce<<<dim3(128), dim3(256), 0, stream>>>(part, t, g);
    k_final<<<dim3(1), dim3(256), 0, stream>>>(t, z0, g, yg, out, (it == 2) ? 1 : 0);
  }
}

// Round 6
// 244.936 us; speedup vs baseline: 5.0331x; 1.2668x over previous
//
#include <hip/hip_runtime.h>
#include <hip/hip_fp16.h>

// Problem constants
#define D_  128
#define T_  128
#define P_  255           // 2T-1 evaluation points
#define SROW 8320         // 65*128 (64 hden rows + 1 fybar row)
#define NCH  33
#define GSZ  32640        // 255*128

// workspace offsets (float slots)
#define OFF_YG    0          // float yg[16384]
#define OFF_YGT   16384      // half ygT[128 d][128 g]   (8192 floats)
#define OFF_COEF  24576      // float coef[512]
#define OFF_AINV  25088      // float Ainv[16384]
#define OFF_G     41472      // float G[16384]
#define OFF_E     57856      // half E[255*32*128]       (522240 floats)
#define OFF_HDW   580096     // half HDW[255*2080]       (265200 floats)
#define OFF_W1T   845296     // half W1T[256 c][128 d]   (16384 floats)
#define OFF_W2T   861680     // half W2T[128 j][256 c]   (16384 floats)
#define OFF_WT    878064     // float WT[65*16384]
#define OFF_S     1943024    // half S[255*8320]         (1060800 floats)
#define OFF_PART  3003824    // float part[33*32640]
#define OFF_G2    4080944    // float g[32640]
// end = 4113584 floats = 15.7 MiB (round-1 proved >= 16.5 MiB available)

typedef _Float16 f16;
typedef _Float16 f16x4 __attribute__((ext_vector_type(4)));
typedef float f32x4 __attribute__((ext_vector_type(4)));

__device__ __forceinline__ float tanh_fast(float x) {
  float e = __expf(2.0f * x);
  return 1.0f - 2.0f / (e + 1.0f);
}

// Fragment read from swizzled row-major [rows][K] f16 LDS buffer.
// kunits = K/4. Lane provides 4 halves at (row, k = kk*16 + 4*(lane>>4)).
__device__ __forceinline__ f16x4 ldfrag(const f16* buf, int row, int kunits,
                                        int kk, int g) {
  int u = row * kunits + ((kk * 4 + g) ^ (row & 7));
  return *(const f16x4*)(buf + 4 * u);
}

__global__ __launch_bounds__(256) void k_init(const float* __restrict__ z0,
                                              float* __restrict__ yg,
                                              __half* __restrict__ ygT) {
  int idx = blockIdx.x * 256 + threadIdx.x;
  if (idx < T_ * D_) {
    int grow = idx >> 7, d = idx & 127;
    float v = z0[d];
    yg[idx] = v;
    ygT[d * 128 + grow] = __float2half(v);
  }
}

// Tridiagonal inverse: thread d solves A x = e_d (Thomas). Also writes invh.
__global__ __launch_bounds__(128) void k_inv(const float* __restrict__ t,
                                             float* __restrict__ coef,
                                             float* __restrict__ Ainv) {
  __shared__ float tl[128];
  __shared__ float cpL[128], imL[128];
  __shared__ float dpL[127 * 128];
  int d = threadIdx.x;
  tl[d] = t[d];
  __syncthreads();
  if (d == 0) {
    cpL[0] = 0.0f;
    float cprev = 0.0f;
    for (int i = 1; i <= 126; ++i) {
      float hm = tl[i] - tl[i - 1], hi = tl[i + 1] - tl[i];
      float m = 2.0f * (hm + hi) - hm * cprev;
      float im = 1.0f / m;
      imL[i] = im;
      cprev = hi * im;
      cpL[i] = cprev;
    }
  }
  if (d < 127) coef[256 + d] = 1.0f / (tl[d + 1] - tl[d]);   // invh
  __syncthreads();
  float dprev = (d == 0) ? 1.0f : 0.0f;
  dpL[d] = dprev;
  for (int i = 1; i <= 126; ++i) {
    float rhs = (i == d) ? 1.0f : 0.0f;
    float hm = tl[i] - tl[i - 1];
    dprev = (rhs - hm * dprev) * imL[i];
    dpL[i * 128 + d] = dprev;
  }
  float x = (d == 127) ? 1.0f : 0.0f;   // row 127 of A is identity
  Ainv[127 * 128 + d] = x;
  for (int i = 126; i >= 0; --i) {
    x = dpL[i * 128 + d] - cpL[i] * x;
    Ainv[i * 128 + d] = x;
  }
}

// G = Ainv @ R (R = tridiagonal rhs operator; rows 0,127 zero)
__global__ __launch_bounds__(256) void k_G(const float* __restrict__ coef,
                                           const float* __restrict__ Ainv,
                                           float* __restrict__ G) {
  int idx = blockIdx.x * 256 + threadIdx.x;
  int a = idx >> 7, b = idx & 127;
  const float* ih = coef + 256;
  float acc = 0.0f;
  if (b >= 2)             acc += Ainv[a * 128 + b - 1] * (6.0f * ih[b - 1]);
  if (b >= 1 && b <= 126) acc += Ainv[a * 128 + b] * (-6.0f * (ih[b - 1] + ih[b]));
  if (b <= 125)           acc += Ainv[a * 128 + b + 1] * (6.0f * ih[b]);
  G[idx] = acc;
}

// E rows (spline-eval operator) + wq-folded hden table. Iteration-invariant.
__global__ __launch_bounds__(256) void k_EH(const float* __restrict__ t,
                                            const float* __restrict__ Wk1,
                                            const float* __restrict__ bk1,
                                            const float* __restrict__ G,
                                            __half* __restrict__ E,
                                            __half* __restrict__ HDW) {
  __shared__ float tl[128];
  __shared__ float sn[32], an[32], bn[32], cA[32], cB[32];
  __shared__ int idn[32];
  int p = blockIdx.x, tid = threadIdx.x;
  if (tid < 128) tl[tid] = t[tid];
  __syncthreads();
  float xp = (p < T_) ? tl[p] : 0.5f * (tl[p - T_] + tl[p - T_ + 1]);
  if (tid < 32) {
    int n = tid;
    float u = (float)n * (1.0f / 31.0f);
    float q = xp * u;
    float qc = fminf(fmaxf(q, tl[0]), tl[127]);
    int i = (int)floorf(qc * 127.0f);
    i = max(0, min(126, i));
    while (i > 0 && qc < tl[i]) --i;
    while (i < 126 && qc >= tl[i + 1]) ++i;
    float h = tl[i + 1] - tl[i];
    float a = (tl[i + 1] - qc) / h, b = (qc - tl[i]) / h;
    sn[n] = q; idn[n] = i; an[n] = a; bn[n] = b;
    float h26 = h * h * (1.0f / 6.0f);
    cA[n] = (a * a * a - a) * h26;
    cB[n] = (b * b * b - b) * h26;
  }
  __syncthreads();
  #pragma unroll
  for (int pass = 0; pass < 16; ++pass) {
    int n = pass * 2 + (tid >> 7);
    int b = tid & 127;
    int i = idn[n];
    float v = cA[n] * G[i * 128 + b] + cB[n] * G[(i + 1) * 128 + b];
    if (b == i) v += an[n];
    if (b == i + 1) v += bn[n];
    E[(p * 32 + n) * 128 + b] = __float2half(v);
  }
  #pragma unroll
  for (int k = 0; k < 9; ++k) {
    int idx = k * 256 + tid;
    if (idx < 2080) {
      int c = idx >> 5, n = idx & 31;
      float wq = (n == 0 || n == 31) ? 0.5f : 1.0f;
      float v = (c < 64)
          ? wq * tanh_fast(fmaf(xp, Wk1[c], fmaf(sn[n], Wk1[64 + c], bk1[c])))
          : wq;
      HDW[p * 2080 + idx] = __float2half(v);   // layout [c][n]
    }
  }
}

// WT[c][j][i] = Wrow_c[i*128+j]
__global__ __launch_bounds__(256) void k_transpose(const float* __restrict__ Wk2,
                                                   const float* __restrict__ bk2,
                                                   float* __restrict__ WT) {
  int c = blockIdx.x;
  const float* src = (c < 64) ? (Wk2 + c * 16384) : bk2;
  __shared__ float tile[16384];
  #pragma unroll 8
  for (int k = 0; k < 64; ++k) {
    int idx = k * 256 + threadIdx.x;
    int i = idx >> 7, j = idx & 127;
    tile[j * 128 + (i ^ (j & 31))] = src[idx];
  }
  __syncthreads();
  float* dst = WT + c * 16384;
  #pragma unroll 8
  for (int k = 0; k < 64; ++k) {
    int idx = k * 256 + threadIdx.x;
    int jj = idx >> 7, ii = idx & 127;
    dst[idx] = tile[jj * 128 + (ii ^ (jj & 31))];
  }
}

// One-time f16 transposed weights: W1T[c][d], W2T[j][c]
__global__ __launch_bounds__(256) void k_prepW(const float* __restrict__ W1,
                                               const float* __restrict__ W2,
                                               __half* __restrict__ W1T,
                                               __half* __restrict__ W2T) {
  int idx = blockIdx.x * 256 + threadIdx.x;   // 256 blocks -> 65536
  if (idx < 32768) {
    int c = idx >> 7, d = idx & 127;
    W1T[idx] = __float2half(W1[d * 256 + c]);
  } else {
    int k = idx - 32768;
    int j = k >> 8, c = k & 255;
    W2T[k] = __float2half(W2[c * 128 + j]);
  }
}

// Fused per-p chain via MFMA: ys = E@yg -> h1 = tanh(ys@W1+b1)
// -> fy = h1@W2+b2 -> S = hdw@fy. One block per p, 4 waves.
__global__ __launch_bounds__(256) void k_fused(
    const __half* __restrict__ ygT, const __half* __restrict__ E,
    const __half* __restrict__ HDW,
    const __half* __restrict__ W1T, const __half* __restrict__ W2T,
    const float* __restrict__ b1, const float* __restrict__ b2,
    __half* __restrict__ Sh) {
  __shared__ __align__(16) unsigned char smem[65536];
  f16* RW = (f16*)smem;              // 16384 h: ygT -> W1T chunks -> W2T chunks
  f16* RA = (f16*)(smem + 32768);    // 4096 h: E -> fyT[128 j][32 n]
  f16* RB = (f16*)(smem + 40960);    // 4096 h: ys[32][128] -> hdw[80][32]
  f16* RC = (f16*)(smem + 49152);    // 8192 h: h1[32][256]
  int p = blockIdx.x, tid = threadIdx.x;
  int wv = tid >> 6, l = tid & 63, g = l >> 4, r = l & 15;

  // stage ygT -> RW, E_p -> RA (swizzled: unit4 k4 ^= row&7)
  {
    const uint2* src = (const uint2*)ygT;
    uint2* dst = (uint2*)RW;
    #pragma unroll
    for (int k = 0; k < 16; ++k) {
      int idx = k * 256 + tid;
      int row = idx >> 5, k4 = idx & 31;
      dst[row * 32 + (k4 ^ (row & 7))] = src[idx];
    }
    const uint2* se = (const uint2*)(E + p * 4096);
    uint2* da = (uint2*)RA;
    #pragma unroll
    for (int k = 0; k < 4; ++k) {
      int idx = k * 256 + tid;
      int row = idx >> 5, k4 = idx & 31;
      da[row * 32 + (k4 ^ (row & 7))] = se[idx];
    }
  }
  __syncthreads();
  // ys[32][128] = E[32][128] @ yg : A=RA, B^T=RW -> RB
  for (int t = wv; t < 16; t += 4) {
    int mt = t >> 3, nt = t & 7;
    f32x4 acc = {0.f, 0.f, 0.f, 0.f};
    #pragma unroll
    for (int kk = 0; kk < 8; ++kk) {
      f16x4 a = ldfrag(RA, mt * 16 + r, 32, kk, g);
      f16x4 b = ldfrag(RW, nt * 16 + r, 32, kk, g);
      acc = __builtin_amdgcn_mfma_f32_16x16x16f16(a, b, acc, 0, 0, 0);
    }
    int col = nt * 16 + r;
    #pragma unroll
    for (int i = 0; i < 4; ++i) {
      int row = mt * 16 + g * 4 + i;
      RB[row * 128 + (col ^ ((row & 7) << 2))] = (f16)acc[i];
    }
  }
  // h1[32][256] = tanh(ys @ W1 + b1): two 128-col halves, W1T chunk in RW
  for (int hf = 0; hf < 2; ++hf) {
    __syncthreads();
    {
      const uint2* src = (const uint2*)(W1T + hf * 16384);
      uint2* dst = (uint2*)RW;
      #pragma unroll
      for (int k = 0; k < 16; ++k) {
        int idx = k * 256 + tid;
        int row = idx >> 5, k4 = idx & 31;
        dst[row * 32 + (k4 ^ (row & 7))] = src[idx];
      }
    }
    __syncthreads();
    int c0 = hf * 128;
    for (int t = wv; t < 16; t += 4) {
      int mt = t >> 3, nt = t & 7;
      f32x4 acc = {0.f, 0.f, 0.f, 0.f};
      #pragma unroll
      for (int kk = 0; kk < 8; ++kk) {
        f16x4 a = ldfrag(RB, mt * 16 + r, 32, kk, g);
        f16x4 b = ldfrag(RW, nt * 16 + r, 32, kk, g);
        acc = __builtin_amdgcn_mfma_f32_16x16x16f16(a, b, acc, 0, 0, 0);
      }
      int colg = c0 + nt * 16 + r;
      float bias = b1[colg];
      #pragma unroll
      for (int i = 0; i < 4; ++i) {
        int row = mt * 16 + g * 4 + i;
        RC[row * 256 + (colg ^ ((row & 7) << 2))] = (f16)tanh_fast(acc[i] + bias);
      }
    }
  }
  __syncthreads();
  // stage hdw[80][32] (zero-padded) -> RB, W2T chunk0 -> RW
  {
    const uint2* sh_ = (const uint2*)(HDW + p * 2080);
    uint2* db = (uint2*)RB;
    #pragma unroll
    for (int k = 0; k < 3; ++k) {
      int idx = k * 256 + tid;
      if (idx < 640) {
        int row = idx >> 3, k4 = idx & 7;
        uint2 v = (idx < 520) ? sh_[idx] : make_uint2(0u, 0u);
        db[row * 8 + (k4 ^ (row & 7))] = v;
      }
    }
    const uint2* src = (const uint2*)W2T;
    uint2* dst = (uint2*)RW;
    #pragma unroll
    for (int k = 0; k < 16; ++k) {
      int idx = k * 256 + tid;
      int row = idx >> 6, k4 = idx & 63;
      dst[row * 64 + (k4 ^ (row & 7))] = src[idx];
    }
  }
  __syncthreads();
  // fy[32][128] = h1 @ W2 + b2, stored TRANSPOSED as fyT[j][n] in RA
  for (int hf = 0; hf < 2; ++hf) {
    if (hf) {
      __syncthreads();
      const uint2* src = (const uint2*)(W2T + 16384);
      uint2* dst = (uint2*)RW;
      #pragma unroll
      for (int k = 0; k < 16; ++k) {
        int idx = k * 256 + tid;
        int row = idx >> 6, k4 = idx & 63;
        dst[row * 64 + (k4 ^ (row & 7))] = src[idx];
      }
      __syncthreads();
    }
    int j0 = hf * 64;
    for (int t = wv; t < 8; t += 4) {
      int mt = t >> 2, nt = t & 3;
      f32x4 acc = {0.f, 0.f, 0.f, 0.f};
      #pragma unroll
      for (int kk = 0; kk < 16; ++kk) {
        f16x4 a = ldfrag(RC, mt * 16 + r, 64, kk, g);
        f16x4 b = ldfrag(RW, nt * 16 + r, 64, kk, g);
        acc = __builtin_amdgcn_mfma_f32_16x16x16f16(a, b, acc, 0, 0, 0);
      }
      int jg = j0 + nt * 16 + r;
      float bias = b2[jg];
      #pragma unroll
      for (int i = 0; i < 4; ++i) {
        int n = mt * 16 + g * 4 + i;
        RA[jg * 32 + (n ^ ((jg & 7) << 2))] = (f16)(acc[i] + bias);
      }
    }
  }
  __syncthreads();
  // S[80][128] = hdw[80][32] @ fy[32][128]; write rows c<65 to global
  for (int t = wv; t < 40; t += 4) {
    int mt = t >> 3, nt = t & 7;
    f32x4 acc = {0.f, 0.f, 0.f, 0.f};
    #pragma unroll
    for (int kk = 0; kk < 2; ++kk) {
      f16x4 a = ldfrag(RB, mt * 16 + r, 8, kk, g);
      f16x4 b = ldfrag(RA, nt * 16 + r, 8, kk, g);
      acc = __builtin_amdgcn_mfma_f32_16x16x16f16(a, b, acc, 0, 0, 0);
    }
    #pragma unroll
    for (int i = 0; i < 4; ++i) {
      int c = mt * 16 + g * 4 + i;
      if (c < 65) Sh[p * SROW + c * 128 + nt * 16 + r] = __float2half(acc[i]);
    }
  }
}

// partial[cc][p][i] = sum over k in c-chunk cc of S[p][k]*WT[k][i]
__global__ __launch_bounds__(256) void k_gemm(const __half* __restrict__ Sh,
                                              const float* __restrict__ WT,
                                              float* __restrict__ part) {
  int pt = blockIdx.x;   // 0..16
  int cc = blockIdx.y;   // 0..32
  int c0 = cc * 2;
  int nk = (c0 + 1 < 65) ? 256 : 128;
  int p0 = pt * 15;
  int tid = threadIdx.x;
  __shared__ float Sl[15 * 256];
  for (int idx = tid; idx < 15 * 256; idx += 256) {
    int pl = idx >> 8, kk = idx & 255;
    Sl[idx] = (kk < nk) ? __half2float(Sh[(p0 + pl) * SROW + c0 * 128 + kk]) : 0.0f;
  }
  __syncthreads();
  int i4 = (tid & 31) * 4;
  int grp = tid >> 5;
  int grp2 = (grp < 7) ? grp + 8 : grp;
  const float* wb = WT + c0 * 16384 + i4;
  float a0[4] = {0.f, 0.f, 0.f, 0.f};
  float a1[4] = {0.f, 0.f, 0.f, 0.f};
  #pragma unroll 8
  for (int kk = 0; kk < nk; ++kk) {
    float4 w = *(const float4*)&wb[kk * 128];
    float s0 = Sl[grp * 256 + kk];
    float s1 = Sl[grp2 * 256 + kk];
    a0[0] = fmaf(w.x, s0, a0[0]); a0[1] = fmaf(w.y, s0, a0[1]);
    a0[2] = fmaf(w.z, s0, a0[2]); a0[3] = fmaf(w.w, s0, a0[3]);
    a1[0] = fmaf(w.x, s1, a1[0]); a1[1] = fmaf(w.y, s1, a1[1]);
    a1[2] = fmaf(w.z, s1, a1[2]); a1[3] = fmaf(w.w, s1, a1[3]);
  }
  *(float4*)&part[cc * GSZ + (p0 + grp) * 128 + i4] =
      make_float4(a0[0], a0[1], a0[2], a0[3]);
  if (grp < 7)
    *(float4*)&part[cc * GSZ + (p0 + grp + 8) * 128 + i4] =
        make_float4(a1[0], a1[1], a1[2], a1[3]);
}

__global__ __launch_bounds__(256) void k_reduce(const float* __restrict__ part,
                                                const float* __restrict__ t,
                                                float* __restrict__ g) {
  int idx = blockIdx.x * 256 + threadIdx.x;
  if (idx >= GSZ) return;
  float s = 0.f;
  #pragma unroll
  for (int cc = 0; cc < NCH; ++cc) s += part[cc * GSZ + idx];
  int p = idx >> 7;
  float xp = (p < T_) ? t[p] : 0.5f * (t[p - T_] + t[p - T_ + 1]);
  g[idx] = s * (xp * (1.0f / 31.0f));
}

__global__ __launch_bounds__(256) void k_final(const float* __restrict__ t,
                                               const float* __restrict__ z0,
                                               const float* __restrict__ g,
                                               float* __restrict__ yg,
                                               __half* __restrict__ ygT,
                                               float* __restrict__ out, int wout) {
  __shared__ float inc[127 * 128];
  int tid = threadIdx.x;
  for (int idx = tid; idx < 127 * 128; idx += 256) {
    int k = idx >> 7, d = idx & 127;
    float h = t[k + 1] - t[k];
    inc[idx] = h * (1.0f / 6.0f) *
        (g[k * 128 + d] + 4.0f * g[(T_ + k) * 128 + d] + g[(k + 1) * 128 + d]);
  }
  __syncthreads();
  if (tid < 128) {
    int d = tid;
    float acc = z0[d];
    yg[d] = acc;
    ygT[d * 128] = __float2half(acc);
    if (wout) out[d] = acc;
    #pragma unroll 4
    for (int k = 0; k < 127; ++k) {
      acc += inc[k * 128 + d];
      yg[(k + 1) * 128 + d] = acc;
      ygT[d * 128 + k + 1] = __float2half(acc);
      if (wout) out[(k + 1) * 128 + d] = acc;
    }
  }
}

extern "C" void kernel_launch(void* const* d_in, const int* in_sizes, int n_in,
                              void* d_out, int out_size, void* d_ws, size_t ws_size,
                              hipStream_t stream) {
  const float* z0  = (const float*)d_in[0];
  const float* t   = (const float*)d_in[1];
  const float* W1  = (const float*)d_in[2];
  const float* b1  = (const float*)d_in[3];
  const float* W2  = (const float*)d_in[4];
  const float* b2  = (const float*)d_in[5];
  const float* Wk1 = (const float*)d_in[6];
  const float* bk1 = (const float*)d_in[7];
  const float* Wk2 = (const float*)d_in[8];
  const float* bk2 = (const float*)d_in[9];
  float* out = (float*)d_out;
  float* ws  = (float*)d_ws;

  float*  yg   = ws + OFF_YG;
  __half* ygT  = (__half*)(ws + OFF_YGT);
  float*  coef = ws + OFF_COEF;
  float*  Ainv = ws + OFF_AINV;
  float*  G    = ws + OFF_G;
  __half* E    = (__half*)(ws + OFF_E);
  __half* HDW  = (__half*)(ws + OFF_HDW);
  __half* W1Th = (__half*)(ws + OFF_W1T);
  __half* W2Th = (__half*)(ws + OFF_W2T);
  float*  WT   = ws + OFF_WT;
  __half* Sh   = (__half*)(ws + OFF_S);
  float*  part = ws + OFF_PART;
  float*  g    = ws + OFF_G2;

  k_init<<<dim3(64), dim3(256), 0, stream>>>(z0, yg, ygT);
  k_inv<<<dim3(1), dim3(128), 0, stream>>>(t, coef, Ainv);
  k_transpose<<<dim3(65), dim3(256), 0, stream>>>(Wk2, bk2, WT);
  k_prepW<<<dim3(256), dim3(256), 0, stream>>>(W1, W2, W1Th, W2Th);
  k_G<<<dim3(64), dim3(256), 0, stream>>>(coef, Ainv, G);
  k_EH<<<dim3(255), dim3(256), 0, stream>>>(t, Wk1, bk1, G, E, HDW);
  for (int it = 0; it < 3; ++it) {
    k_fused<<<dim3(255), dim3(256), 0, stream>>>(ygT, E, HDW, W1Th, W2Th,
                                                 b1, b2, Sh);
    k_gemm<<<dim3(17, NCH), dim3(256), 0, stream>>>(Sh, WT, part);
    k_reduce<<<dim3(128), dim3(256), 0, stream>>>(part, t, g);
    k_final<<<dim3(1), dim3(256), 0, stream>>>(t, z0, g, yg, ygT, out,
                                               (it == 2) ? 1 : 0);
  }
}

// Round 9
// 208.716 us; speedup vs baseline: 5.9065x; 1.1735x over previous
//
#include <hip/hip_runtime.h>
#include <hip/hip_fp16.h>

// Problem constants
#define D_  128
#define T_  128
#define P_  255           // 2T-1 evaluation points
#define SROW 8320         // 65*128 (64 hden rows + 1 fybar row)
#define GSZ  32640        // 255*128

// workspace offsets (float slots) — sizes:
//   ygT 8192 | coef 512 | Ainv 16384 | G 16384 | E 522240 | HDW 265200
//   W1T 16384 | W2T 16384 | WTT[128][8320]h = 532480 | Sh 256*8320h = 1064960
//   g 32640  -> end 2491760 floats = 9.5 MiB
#define OFF_YGT   0
#define OFF_COEF  8192
#define OFF_AINV  8704
#define OFF_G     25088
#define OFF_E     41472
#define OFF_HDW   563712
#define OFF_W1T   828912
#define OFF_W2T   845296
#define OFF_WTT   861680
#define OFF_S     1394160
#define OFF_G2    2459120

typedef _Float16 f16;
typedef _Float16 f16x4 __attribute__((ext_vector_type(4)));
typedef float f32x4 __attribute__((ext_vector_type(4)));

__device__ __forceinline__ float tanh_fast(float x) {
  float e = __expf(2.0f * x);
  return 1.0f - 2.0f / (e + 1.0f);
}

// Fragment read from swizzled row-major [rows][K] f16 LDS buffer.
// kunits = K/4. Lane provides 4 halves at (row, k = kk*16 + 4*quad).
__device__ __forceinline__ f16x4 ldfrag(const f16* buf, int row, int kunits,
                                        int kk, int quad) {
  int u = row * kunits + ((kk * 4 + quad) ^ (row & 7));
  return *(const f16x4*)(buf + 4 * u);
}

// ---- setup: ygT init, W1T/W2T f16 transposes, WTT relayout, Thomas inverse --
__global__ __launch_bounds__(256) void k_setup(
    const float* __restrict__ z0, const float* __restrict__ tgrid,
    const float* __restrict__ W1, const float* __restrict__ W2,
    const float* __restrict__ Wk2, const float* __restrict__ bk2,
    __half* __restrict__ ygT, float* __restrict__ coef,
    float* __restrict__ Ainv, __half* __restrict__ W1T,
    __half* __restrict__ W2T, __half* __restrict__ WTT) {
  __shared__ __align__(16) unsigned char smem[66560];
  int bid = blockIdx.x, tid = threadIdx.x;
  // grid-stride WTT relayout: WTT[i][c*128+j] = (c<64 ? Wk2[c][i][j] : bk2[i][j])
  for (int idx = bid * 256 + tid; idx < 65 * 16384; idx += 256 * 256) {
    int c = idx >> 14, rem = idx & 16383;
    int i = rem >> 7, j = rem & 127;
    float v = (c < 64) ? Wk2[idx] : bk2[rem];
    WTT[i * 8320 + c * 128 + j] = __float2half(v);
  }
  if (bid == 0) {
    for (int idx = tid; idx < 16384; idx += 256) {
      int grow = idx >> 7, d = idx & 127;
      ygT[d * 128 + grow] = __float2half(z0[d]);
    }
  } else if (bid == 1) {
    for (int idx = tid; idx < 32768; idx += 256) {
      int c = idx >> 7, d = idx & 127;
      W1T[idx] = __float2half(W1[d * 256 + c]);
    }
  } else if (bid == 2) {
    for (int idx = tid; idx < 32768; idx += 256) {
      int j = idx >> 8, c2 = idx & 255;
      W2T[idx] = __float2half(W2[c2 * 128 + j]);
    }
  } else if (bid == 255) {   // tridiagonal inverse (Thomas per column)
    float* dpL = (float*)smem;              // 127*128 floats
    float* tl  = (float*)(smem + 65024);    // 128
    float* cpL = tl + 128;
    float* imL = cpL + 128;
    if (tid < 128) tl[tid] = tgrid[tid];
    __syncthreads();
    if (tid == 0) {
      cpL[0] = 0.0f;
      float cprev = 0.0f;
      for (int i = 1; i <= 126; ++i) {
        float hm = tl[i] - tl[i - 1], hi = tl[i + 1] - tl[i];
        float m = 2.0f * (hm + hi) - hm * cprev;
        float im = 1.0f / m;
        imL[i] = im;
        cprev = hi * im;
        cpL[i] = cprev;
      }
    }
    if (tid < 127) coef[256 + tid] = 1.0f / (tl[tid + 1] - tl[tid]);
    __syncthreads();
    if (tid < 128) {
      int d = tid;
      float dprev = (d == 0) ? 1.0f : 0.0f;
      dpL[d] = dprev;
      for (int i = 1; i <= 126; ++i) {
        float rhs = (i == d) ? 1.0f : 0.0f;
        float hm = tl[i] - tl[i - 1];
        dprev = (rhs - hm * dprev) * imL[i];
        dpL[i * 128 + d] = dprev;
      }
      float x = (d == 127) ? 1.0f : 0.0f;
      Ainv[127 * 128 + d] = x;
      for (int i = 126; i >= 0; --i) {
        x = dpL[i * 128 + d] - cpL[i] * x;
        Ainv[i * 128 + d] = x;
      }
    }
  }
}

// G = Ainv @ R (R = tridiagonal rhs operator; rows 0,127 zero)
__global__ __launch_bounds__(256) void k_G(const float* __restrict__ coef,
                                           const float* __restrict__ Ainv,
                                           float* __restrict__ G) {
  int idx = blockIdx.x * 256 + threadIdx.x;
  int a = idx >> 7, b = idx & 127;
  const float* ih = coef + 256;
  float acc = 0.0f;
  if (b >= 2)             acc += Ainv[a * 128 + b - 1] * (6.0f * ih[b - 1]);
  if (b >= 1 && b <= 126) acc += Ainv[a * 128 + b] * (-6.0f * (ih[b - 1] + ih[b]));
  if (b <= 125)           acc += Ainv[a * 128 + b + 1] * (6.0f * ih[b]);
  G[idx] = acc;
}

// E rows (spline-eval operator) + wq-folded hden table. Iteration-invariant.
__global__ __launch_bounds__(256) void k_EH(const float* __restrict__ t,
                                            const float* __restrict__ Wk1,
                                            const float* __restrict__ bk1,
                                            const float* __restrict__ G,
                                            __half* __restrict__ E,
                                            __half* __restrict__ HDW) {
  __shared__ float tl[128];
  __shared__ float sn[32], an[32], bn[32], cA[32], cB[32];
  __shared__ int idn[32];
  int p = blockIdx.x, tid = threadIdx.x;
  if (tid < 128) tl[tid] = t[tid];
  __syncthreads();
  float xp = (p < T_) ? tl[p] : 0.5f * (tl[p - T_] + tl[p - T_ + 1]);
  if (tid < 32) {
    int n = tid;
    float u = (float)n * (1.0f / 31.0f);
    float q = xp * u;
    float qc = fminf(fmaxf(q, tl[0]), tl[127]);
    int i = (int)floorf(qc * 127.0f);
    i = max(0, min(126, i));
    while (i > 0 && qc < tl[i]) --i;
    while (i < 126 && qc >= tl[i + 1]) ++i;
    float h = tl[i + 1] - tl[i];
    float aa = (tl[i + 1] - qc) / h, bb = (qc - tl[i]) / h;
    sn[n] = q; idn[n] = i; an[n] = aa; bn[n] = bb;
    float h26 = h * h * (1.0f / 6.0f);
    cA[n] = (aa * aa * aa - aa) * h26;
    cB[n] = (bb * bb * bb - bb) * h26;
  }
  __syncthreads();
  #pragma unroll
  for (int pass = 0; pass < 16; ++pass) {
    int n = pass * 2 + (tid >> 7);
    int b = tid & 127;
    int i = idn[n];
    float v = cA[n] * G[i * 128 + b] + cB[n] * G[(i + 1) * 128 + b];
    if (b == i) v += an[n];
    if (b == i + 1) v += bn[n];
    E[(p * 32 + n) * 128 + b] = __float2half(v);
  }
  #pragma unroll
  for (int k = 0; k < 9; ++k) {
    int idx = k * 256 + tid;
    if (idx < 2080) {
      int c = idx >> 5, n = idx & 31;
      float wq = (n == 0 || n == 31) ? 0.5f : 1.0f;
      float v = (c < 64)
          ? wq * tanh_fast(fmaf(xp, Wk1[c], fmaf(sn[n], Wk1[64 + c], bk1[c])))
          : wq;
      HDW[p * 2080 + idx] = __float2half(v);   // layout [c][n]
    }
  }
}

// Fused per-p chain via MFMA (verbatim round-6 body) + g/Sh-row-255 zeroing.
__global__ __launch_bounds__(256) void k_fused(
    const __half* __restrict__ ygT, const __half* __restrict__ E,
    const __half* __restrict__ HDW,
    const __half* __restrict__ W1T, const __half* __restrict__ W2T,
    const float* __restrict__ b1, const float* __restrict__ b2,
    __half* __restrict__ Sh, float* __restrict__ g) {
  __shared__ __align__(16) unsigned char smem[65536];
  f16* RW = (f16*)smem;              // 16384 h
  f16* RA = (f16*)(smem + 32768);    // 4096 h
  f16* RB = (f16*)(smem + 40960);    // 4096 h
  f16* RC = (f16*)(smem + 49152);    // 8192 h
  int p = blockIdx.x, tid = threadIdx.x;
  int wv = tid >> 6, l = tid & 63, quad = l >> 4, r = l & 15;

  if (tid < 128) g[p * 128 + tid] = 0.0f;          // zero g for atomic phase
  if (p == 0) {                                     // keep pad row finite/zero
    unsigned* zrow = (unsigned*)(Sh + 255 * SROW);
    for (int z = tid; z < SROW / 2; z += 256) zrow[z] = 0u;
  }

  {
    const uint2* src = (const uint2*)ygT;
    uint2* dst = (uint2*)RW;
    #pragma unroll
    for (int k = 0; k < 16; ++k) {
      int idx = k * 256 + tid;
      int row = idx >> 5, k4 = idx & 31;
      dst[row * 32 + (k4 ^ (row & 7))] = src[idx];
    }
    const uint2* se = (const uint2*)(E + p * 4096);
    uint2* da = (uint2*)RA;
    #pragma unroll
    for (int k = 0; k < 4; ++k) {
      int idx = k * 256 + tid;
      int row = idx >> 5, k4 = idx & 31;
      da[row * 32 + (k4 ^ (row & 7))] = se[idx];
    }
  }
  __syncthreads();
  // ys[32][128] = E @ yg
  for (int tt = wv; tt < 16; tt += 4) {
    int mt = tt >> 3, nt = tt & 7;
    f32x4 acc = {0.f, 0.f, 0.f, 0.f};
    #pragma unroll
    for (int kk = 0; kk < 8; ++kk) {
      f16x4 av = ldfrag(RA, mt * 16 + r, 32, kk, quad);
      f16x4 bv = ldfrag(RW, nt * 16 + r, 32, kk, quad);
      acc = __builtin_amdgcn_mfma_f32_16x16x16f16(av, bv, acc, 0, 0, 0);
    }
    int col = nt * 16 + r;
    #pragma unroll
    for (int i = 0; i < 4; ++i) {
      int row = mt * 16 + quad * 4 + i;
      RB[row * 128 + (col ^ ((row & 7) << 2))] = (f16)acc[i];
    }
  }
  // h1[32][256] = tanh(ys @ W1 + b1)
  for (int hf = 0; hf < 2; ++hf) {
    __syncthreads();
    {
      const uint2* src = (const uint2*)(W1T + hf * 16384);
      uint2* dst = (uint2*)RW;
      #pragma unroll
      for (int k = 0; k < 16; ++k) {
        int idx = k * 256 + tid;
        int row = idx >> 5, k4 = idx & 31;
        dst[row * 32 + (k4 ^ (row & 7))] = src[idx];
      }
    }
    __syncthreads();
    int c0 = hf * 128;
    for (int tt = wv; tt < 16; tt += 4) {
      int mt = tt >> 3, nt = tt & 7;
      f32x4 acc = {0.f, 0.f, 0.f, 0.f};
      #pragma unroll
      for (int kk = 0; kk < 8; ++kk) {
        f16x4 av = ldfrag(RB, mt * 16 + r, 32, kk, quad);
        f16x4 bv = ldfrag(RW, nt * 16 + r, 32, kk, quad);
        acc = __builtin_amdgcn_mfma_f32_16x16x16f16(av, bv, acc, 0, 0, 0);
      }
      int colg = c0 + nt * 16 + r;
      float bias = b1[colg];
      #pragma unroll
      for (int i = 0; i < 4; ++i) {
        int row = mt * 16 + quad * 4 + i;
        RC[row * 256 + (colg ^ ((row & 7) << 2))] = (f16)tanh_fast(acc[i] + bias);
      }
    }
  }
  __syncthreads();
  // stage hdw[80][32] (zero-padded) -> RB, W2T chunk0 -> RW
  {
    const uint2* sh_ = (const uint2*)(HDW + p * 2080);
    uint2* db = (uint2*)RB;
    #pragma unroll
    for (int k = 0; k < 3; ++k) {
      int idx = k * 256 + tid;
      if (idx < 640) {
        int row = idx >> 3, k4 = idx & 7;
        uint2 v = (idx < 520) ? sh_[idx] : make_uint2(0u, 0u);
        db[row * 8 + (k4 ^ (row & 7))] = v;
      }
    }
    const uint2* src = (const uint2*)W2T;
    uint2* dst = (uint2*)RW;
    #pragma unroll
    for (int k = 0; k < 16; ++k) {
      int idx = k * 256 + tid;
      int row = idx >> 6, k4 = idx & 63;
      dst[row * 64 + (k4 ^ (row & 7))] = src[idx];
    }
  }
  __syncthreads();
  // fy[32][128] = h1 @ W2 + b2, stored transposed as fyT[j][n] in RA
  for (int hf = 0; hf < 2; ++hf) {
    if (hf) {
      __syncthreads();
      const uint2* src = (const uint2*)(W2T + 16384);
      uint2* dst = (uint2*)RW;
      #pragma unroll
      for (int k = 0; k < 16; ++k) {
        int idx = k * 256 + tid;
        int row = idx >> 6, k4 = idx & 63;
        dst[row * 64 + (k4 ^ (row & 7))] = src[idx];
      }
      __syncthreads();
    }
    int j0 = hf * 64;
    for (int tt = wv; tt < 8; tt += 4) {
      int mt = tt >> 2, nt = tt & 3;
      f32x4 acc = {0.f, 0.f, 0.f, 0.f};
      #pragma unroll
      for (int kk = 0; kk < 16; ++kk) {
        f16x4 av = ldfrag(RC, mt * 16 + r, 64, kk, quad);
        f16x4 bv = ldfrag(RW, nt * 16 + r, 64, kk, quad);
        acc = __builtin_amdgcn_mfma_f32_16x16x16f16(av, bv, acc, 0, 0, 0);
      }
      int jg = j0 + nt * 16 + r;
      float bias = b2[jg];
      #pragma unroll
      for (int i = 0; i < 4; ++i) {
        int n = mt * 16 + quad * 4 + i;
        RA[jg * 32 + (n ^ ((jg & 7) << 2))] = (f16)(acc[i] + bias);
      }
    }
  }
  __syncthreads();
  // S[80][128] = hdw @ fy
  for (int tt = wv; tt < 40; tt += 4) {
    int mt = tt >> 3, nt = tt & 7;
    f32x4 acc = {0.f, 0.f, 0.f, 0.f};
    #pragma unroll
    for (int kk = 0; kk < 2; ++kk) {
      f16x4 av = ldfrag(RB, mt * 16 + r, 8, kk, quad);
      f16x4 bv = ldfrag(RA, nt * 16 + r, 8, kk, quad);
      acc = __builtin_amdgcn_mfma_f32_16x16x16f16(av, bv, acc, 0, 0, 0);
    }
    #pragma unroll
    for (int i = 0; i < 4; ++i) {
      int c = mt * 16 + quad * 4 + i;
      if (c < 65) Sh[p * SROW + c * 128 + nt * 16 + r] = __float2half(acc[i]);
    }
  }
}

// g[255x128] += S[255x8320] @ WTT^T via MFMA; grid (16 m-tiles, 8 K-chunks).
// A[m=p][k] = Sh row-major; B[k][n=i] = WTT[n][k] (row-major [n][8320]).
__global__ __launch_bounds__(256) void k_gemmM(const __half* __restrict__ Sh,
                                               const __half* __restrict__ WTT,
                                               float* __restrict__ g) {
  int mt = blockIdx.x;      // 0..15
  int kc = blockIdx.y;      // 0..7  (K chunk of 1040)
  int tid = threadIdx.x;
  int wv = tid >> 6, l = tid & 63, q = l >> 4, r = l & 15;
  int p0 = mt * 16;
  const f16* Arow = (const f16*)Sh + (p0 + r) * SROW + kc * 1040 + 4 * q;
  const f16* B0 = (const f16*)WTT + (wv * 32 + r) * 8320 + kc * 1040 + 4 * q;
  const f16* B1 = B0 + 16 * 8320;
  f32x4 acc0 = {0.f, 0.f, 0.f, 0.f}, acc1 = {0.f, 0.f, 0.f, 0.f};
  #pragma unroll 5
  for (int ks = 0; ks < 65; ++ks) {
    f16x4 av = *(const f16x4*)(Arow + ks * 16);
    f16x4 b0 = *(const f16x4*)(B0 + ks * 16);
    f16x4 b1 = *(const f16x4*)(B1 + ks * 16);
    acc0 = __builtin_amdgcn_mfma_f32_16x16x16f16(av, b0, acc0, 0, 0, 0);
    acc1 = __builtin_amdgcn_mfma_f32_16x16x16f16(av, b1, acc1, 0, 0, 0);
  }
  #pragma unroll
  for (int t = 0; t < 4; ++t) {
    int p = p0 + 4 * q + t;
    if (p < 255) {
      atomicAdd(&g[p * 128 + wv * 32 + r], acc0[t]);
      atomicAdd(&g[p * 128 + wv * 32 + 16 + r], acc1[t]);
    }
  }
}

// Simpson + cumsum; xp/(N-1) scale folded into the g reads.
__global__ __launch_bounds__(256) void k_final(const float* __restrict__ t,
                                               const float* __restrict__ z0,
                                               const float* __restrict__ g,
                                               __half* __restrict__ ygT,
                                               float* __restrict__ out, int wout) {
  __shared__ float incL[127 * 128];
  int tid = threadIdx.x;
  for (int idx = tid; idx < 127 * 128; idx += 256) {
    int k = idx >> 7, d = idx & 127;
    float tk = t[k], tk1 = t[k + 1];
    float h = tk1 - tk;
    float sct  = tk * (1.0f / 31.0f);
    float scm  = 0.5f * (tk + tk1) * (1.0f / 31.0f);
    float sct1 = tk1 * (1.0f / 31.0f);
    incL[idx] = h * (1.0f / 6.0f) *
        (g[k * 128 + d] * sct + 4.0f * g[(T_ + k) * 128 + d] * scm +
         g[(k + 1) * 128 + d] * sct1);
  }
  __syncthreads();
  if (tid < 128) {
    int d = tid;
    float acc = z0[d];
    ygT[d * 128] = __float2half(acc);
    if (wout) out[d] = acc;
    #pragma unroll 4
    for (int k = 0; k < 127; ++k) {
      acc += incL[k * 128 + d];
      ygT[d * 128 + k + 1] = __float2half(acc);
      if (wout) out[(k + 1) * 128 + d] = acc;
    }
  }
}

extern "C" void kernel_launch(void* const* d_in, const int* in_sizes, int n_in,
                              void* d_out, int out_size, void* d_ws, size_t ws_size,
                              hipStream_t stream) {
  const float* z0  = (const float*)d_in[0];
  const float* t   = (const float*)d_in[1];
  const float* W1  = (const float*)d_in[2];
  const float* b1  = (const float*)d_in[3];
  const float* W2  = (const float*)d_in[4];
  const float* b2  = (const float*)d_in[5];
  const float* Wk1 = (const float*)d_in[6];
  const float* bk1 = (const float*)d_in[7];
  const float* Wk2 = (const float*)d_in[8];
  const float* bk2 = (const float*)d_in[9];
  float* out = (float*)d_out;
  float* ws  = (float*)d_ws;

  __half* ygT  = (__half*)(ws + OFF_YGT);
  float*  coef = ws + OFF_COEF;
  float*  Ainv = ws + OFF_AINV;
  float*  G    = ws + OFF_G;
  __half* E    = (__half*)(ws + OFF_E);
  __half* HDW  = (__half*)(ws + OFF_HDW);
  __half* W1T  = (__half*)(ws + OFF_W1T);
  __half* W2T  = (__half*)(ws + OFF_W2T);
  __half* WTT  = (__half*)(ws + OFF_WTT);
  __half* Sh   = (__half*)(ws + OFF_S);
  float*  g    = ws + OFF_G2;

  k_setup<<<dim3(256), dim3(256), 0, stream>>>(z0, t, W1, W2, Wk2, bk2,
                                               ygT, coef, Ainv, W1T, W2T, WTT);
  k_G<<<dim3(64), dim3(256), 0, stream>>>(coef, Ainv, G);
  k_EH<<<dim3(255), dim3(256), 0, stream>>>(t, Wk1, bk1, G, E, HDW);
  for (int it = 0; it < 3; ++it) {
    k_fused<<<dim3(255), dim3(256), 0, stream>>>(ygT, E, HDW, W1T, W2T,
                                                 b1, b2, Sh, g);
    k_gemmM<<<dim3(16, 8), dim3(256), 0, stream>>>(Sh, WTT, g);
    k_final<<<dim3(1), dim3(256), 0, stream>>>(t, z0, g, ygT, out,
                                               (it == 2) ? 1 : 0);
  }
}